// Round 14
// baseline (307.736 us; speedup 1.0000x reference)
//
#include <hip/hip_runtime.h>

typedef unsigned short u16;
typedef unsigned int   u32;
typedef float  f32x4  __attribute__((ext_vector_type(4)));
typedef __bf16 bf16x8 __attribute__((ext_vector_type(8)));
typedef u32    u32x4  __attribute__((ext_vector_type(4)));
typedef u32    u32x2  __attribute__((ext_vector_type(2)));

#define Bb  8
#define Nn  1024
#define Dd  256
#define Hh  8
#define HDd 32
#define CAP 96

__device__ __forceinline__ float bf2f(u16 s){
  u32 u = ((u32)s) << 16; float f; __builtin_memcpy(&f, &u, 4); return f;
}
__device__ __forceinline__ u16 f2bf(float f){
  u32 u; __builtin_memcpy(&u, &f, 4);
  u = (u + 0x7fffu + ((u >> 16) & 1u)) >> 16;
  return (u16)u;
}
__device__ __forceinline__ f32x4 mfma16(bf16x8 a, bf16x8 b, f32x4 c){
  return __builtin_amdgcn_mfma_f32_16x16x32_bf16(a, b, c, 0, 0, 0);
}
__device__ __forceinline__ bf16x8 ld_bf8(const u16* p){
  u32x4 u = *(const u32x4*)p; bf16x8 r; __builtin_memcpy(&r, &u, 16); return r;
}

// ---------------- f32 -> bf16 convert ----------------
__global__ void f32_to_bf16(const float* __restrict__ src, u16* __restrict__ dst, int n){
  int i = (blockIdx.x * 256 + threadIdx.x) * 4;
  if (i < n){
    f32x4 v = *(const f32x4*)(src + i);
    u32x2 p;
    p[0] = (u32)f2bf(v[0]) | ((u32)f2bf(v[1]) << 16);
    p[1] = (u32)f2bf(v[2]) | ((u32)f2bf(v[3]) << 16);
    *(u32x2*)(dst + i) = p;
  }
}

// ---------------- fused 5-weight convert + bias concat ----------------
__global__ void conv_w5(const float* __restrict__ w0, const float* __restrict__ wq,
                        const float* __restrict__ wk, const float* __restrict__ wv,
                        const float* __restrict__ wo, u16* __restrict__ dst,
                        const float* __restrict__ bq, const float* __restrict__ bk,
                        const float* __restrict__ bv, float* __restrict__ bqkv){
  if (blockIdx.x == 832){
    int t = threadIdx.x;
    for (int l = 0; l < 3; ++l){
      bqkv[l*768 +       t] = bq[l*256 + t];
      bqkv[l*768 + 256 + t] = bk[l*256 + t];
      bqkv[l*768 + 512 + t] = bv[l*256 + t];
    }
    return;
  }
  int g4 = (blockIdx.x * 256 + threadIdx.x) * 4;
  const float* src;
  int off;
  if (g4 < 65536){ src = w0; off = g4; }
  else {
    int g = g4 - 65536;
    int sec = g / 196608; off = g - sec * 196608;
    src = (sec == 0 ? wq : sec == 1 ? wk : sec == 2 ? wv : wo);
  }
  f32x4 v = *(const f32x4*)(src + off);
  u32x2 p;
  p[0] = (u32)f2bf(v[0]) | ((u32)f2bf(v[1]) << 16);
  p[1] = (u32)f2bf(v[2]) | ((u32)f2bf(v[3]) << 16);
  *(u32x2*)(dst + g4) = p;
}

// ---------------- adj -> bitmask ----------------
__global__ void adj_to_bits(const float* __restrict__ adj, u32* __restrict__ bits){
  int w = blockIdx.x * 256 + threadIdx.x;        // word over [1024][32]
  const float* p = adj + (long)w * 32;
  u32 m = 0;
  #pragma unroll
  for (int t = 0; t < 32; t += 4){
    f32x4 v = *(const f32x4*)(p + t);
    if (v[0] != 0.f) m |= 1u << (t+0);
    if (v[1] != 0.f) m |= 1u << (t+1);
    if (v[2] != 0.f) m |= 1u << (t+2);
    if (v[3] != 0.f) m |= 1u << (t+3);
  }
  bits[w] = m;
}

// ---------------- neighbor list build (CSR, capacity CAP) ----------------
__global__ __launch_bounds__(256) void nbr_build(const u32* __restrict__ bits,
                                                 u16* __restrict__ idx, int* __restrict__ cnt){
  int i = blockIdx.x * 256 + threadIdx.x;        // grid 4
  int c = 0;
  for (int w = 0; w < 32; ++w){
    u32 wd = bits[i*32 + w];
    while (wd){
      int bi = __ffs(wd) - 1; wd &= wd - 1;
      if (c < CAP) idx[(long)i*CAP + c] = (u16)(w*32 + bi);
      ++c;
    }
  }
  cnt[i] = (c < CAP) ? c : CAP;
}

// ---------------- MFMA GEMM (VALIDATED R4-R13) ----------------
template<bool HBC, bool HBR, bool OF, bool OB>
__global__ __launch_bounds__(256,2) void gemm_bt(
    const u16* __restrict__ A, int lda, long sA,
    const u16* __restrict__ Bt, int ldb, long sB,
    float* __restrict__ Cf, u16* __restrict__ Cb, int ldc, long sC,
    int K, const float* __restrict__ bc, long sbc, const float* __restrict__ br)
{
  __shared__ u16 As[128][40];
  __shared__ u16 Bs[128][40];
  const int bz = blockIdx.z;
  const u16* Ap = A + (long)bz * sA;
  const u16* Bp = Bt + (long)bz * sB;
  const long co = (long)bz * sC;
  const int m0 = blockIdx.y * 128, n0 = blockIdx.x * 128;
  const int tid = threadIdx.x, wave = tid >> 6, lane = tid & 63;
  const int arow = lane & 15, agrp = lane >> 4;
  const int wr = (wave >> 1) * 64, wc = (wave & 1) * 64;
  const int srow = tid >> 1, sch = (tid & 1) * 16;
  const u16* ga = Ap + (long)(m0 + srow) * lda + sch;
  const u16* gb = Bp + (long)(n0 + srow) * ldb + sch;
  f32x4 acc[4][4] = {};
  for (int kb = 0; kb < K; kb += 32){
    u32x4 a0 = *(const u32x4*)ga; u32x4 a1 = *(const u32x4*)(ga + 8);
    u32x4 b0 = *(const u32x4*)gb; u32x4 b1 = *(const u32x4*)(gb + 8);
    __syncthreads();
    *(u32x4*)&As[srow][sch] = a0; *(u32x4*)&As[srow][sch + 8] = a1;
    *(u32x4*)&Bs[srow][sch] = b0; *(u32x4*)&Bs[srow][sch + 8] = b1;
    __syncthreads();
    ga += 32; gb += 32;
    bf16x8 af[4], bv[4];
    #pragma unroll
    for (int f = 0; f < 4; ++f){
      af[f] = ld_bf8(&As[wr + f*16 + arow][agrp*8]);
      bv[f] = ld_bf8(&Bs[wc + f*16 + arow][agrp*8]);
    }
    #pragma unroll
    for (int fm = 0; fm < 4; ++fm)
      #pragma unroll
      for (int fn = 0; fn < 4; ++fn)
        acc[fm][fn] = mfma16(af[fm], bv[fn], acc[fm][fn]);
  }
  #pragma unroll
  for (int fm = 0; fm < 4; ++fm){
    #pragma unroll
    for (int fn = 0; fn < 4; ++fn){
      int j = n0 + wc + fn*16 + arow;
      float badd = 0.f;
      if (HBC) badd = bc[(long)bz*sbc + j];
      #pragma unroll
      for (int r = 0; r < 4; ++r){
        int i = m0 + wr + fm*16 + agrp*4 + r;
        float v = acc[fm][fn][r] + badd;
        if (HBR) v += br[i];
        long idx = co + (long)i * ldc + j;
        if (OF) Cf[idx] = v;
        if (OB) Cb[idx] = f2bf(v);
      }
    }
  }
}

// ---------------- sparse attention v7: fused dense-am row build (no memset) ----------------
// grid (256, 8): i0 = blockIdx.x*4, b = blockIdx.y
__global__ __launch_bounds__(256) void attn_sparse(
    const u16* __restrict__ qkv,          // [B*N][768] bf16: q|k|v
    u16* __restrict__ ob,                 // [B*N][256] bf16
    const u16* __restrict__ idxg, const int* __restrict__ cntg,
    float* __restrict__ amv,              // compact dst (dense==0)
    u16* __restrict__ amd, int dense)     // dense dst [B*N][1024] bf16 (dense==1)
{
  __shared__ float qs[4][256];            // q rows, pre-scaled f32
  __shared__ float E[4][CAP][8];          // raw scores -> unnormalized exp
  __shared__ float invl[4][8];            // per-(row,head) 1/sum
  __shared__ u16   idxl[4][CAP];
  __shared__ int   cntl[4];
  __shared__ u16   drow[4][1024];         // dense a_mean rows (dense==1)
  const int b = blockIdx.y, i0 = blockIdx.x * 4;
  const int tid = threadIdx.x, w = tid >> 6, lane = tid & 63;
  const float SCALE = 0.17677669529663687f;   // 1/sqrt(32)

  { int e = tid * 4, rr = e >> 8, c = e & 255;
    u32x2 uv = *(const u32x2*)(qkv + ((long)(b*Nn + i0 + rr)) * 768 + c);
    qs[rr][c+0] = SCALE * bf2f((u16)(uv[0] & 0xffff));
    qs[rr][c+1] = SCALE * bf2f((u16)(uv[0] >> 16));
    qs[rr][c+2] = SCALE * bf2f((u16)(uv[1] & 0xffff));
    qs[rr][c+3] = SCALE * bf2f((u16)(uv[1] >> 16)); }
  for (int s = tid; s < 4*CAP; s += 256){
    int rr = s / CAP, ss = s - rr*CAP;
    idxl[rr][ss] = idxg[(long)(i0 + rr)*CAP + ss];
  }
  if (tid < 4) cntl[tid] = cntg[i0 + tid];
  if (dense){                              // zero dense rows (2048 dwords)
    u32* dz = (u32*)&drow[0][0];
    #pragma unroll
    for (int t = tid; t < 2048; t += 256) dz[t] = 0;
  }
  __syncthreads();

  const int i = i0 + w;
  const int cnt = cntl[w];

  // ---- Phase A: coalesced 512B K-row reads; 8-lane group reduce; 2-way unroll ----
  { const f32x4 qreg = *(const f32x4*)&qs[w][lane*4];
    const int h = lane >> 3;
    int s = 0;
    for (; s + 2 <= cnt; s += 2){
      int ja = idxl[w][s], jb = idxl[w][s+1];
      u32x2 ka = *(const u32x2*)(qkv + ((long)(b*Nn + ja))*768 + 256 + lane*4);
      u32x2 kb = *(const u32x2*)(qkv + ((long)(b*Nn + jb))*768 + 256 + lane*4);
      float pa = qreg[0]*bf2f((u16)(ka[0]&0xffff)) + qreg[1]*bf2f((u16)(ka[0]>>16))
               + qreg[2]*bf2f((u16)(ka[1]&0xffff)) + qreg[3]*bf2f((u16)(ka[1]>>16));
      float pb = qreg[0]*bf2f((u16)(kb[0]&0xffff)) + qreg[1]*bf2f((u16)(kb[0]>>16))
               + qreg[2]*bf2f((u16)(kb[1]&0xffff)) + qreg[3]*bf2f((u16)(kb[1]>>16));
      pa += __shfl_xor(pa, 1, 64); pa += __shfl_xor(pa, 2, 64); pa += __shfl_xor(pa, 4, 64);
      pb += __shfl_xor(pb, 1, 64); pb += __shfl_xor(pb, 2, 64); pb += __shfl_xor(pb, 4, 64);
      if ((lane & 7) == 0){ E[w][s][h] = pa; E[w][s+1][h] = pb; }
    }
    if (s < cnt){
      int ja = idxl[w][s];
      u32x2 ka = *(const u32x2*)(qkv + ((long)(b*Nn + ja))*768 + 256 + lane*4);
      float pa = qreg[0]*bf2f((u16)(ka[0]&0xffff)) + qreg[1]*bf2f((u16)(ka[0]>>16))
               + qreg[2]*bf2f((u16)(ka[1]&0xffff)) + qreg[3]*bf2f((u16)(ka[1]>>16));
      pa += __shfl_xor(pa, 1, 64); pa += __shfl_xor(pa, 2, 64); pa += __shfl_xor(pa, 4, 64);
      if ((lane & 7) == 0) E[w][s][h] = pa;
    }
  }
  __syncthreads();

  // ---- Phase B: per-head max/sum; lane = h*8+k owns slots s==k (mod 8) ----
  { const int h = lane >> 3, k = lane & 7;
    float m = -3.0e38f;
    for (int s = k; s < cnt; s += 8) m = fmaxf(m, E[w][s][h]);
    m = fmaxf(m, __shfl_xor(m, 1, 64));
    m = fmaxf(m, __shfl_xor(m, 2, 64));
    m = fmaxf(m, __shfl_xor(m, 4, 64));
    float l = 0.f;
    for (int s = k; s < cnt; s += 8){
      float e = __expf(E[w][s][h] - m);
      E[w][s][h] = e; l += e;
    }
    l += __shfl_xor(l, 1, 64);
    l += __shfl_xor(l, 2, 64);
    l += __shfl_xor(l, 4, 64);
    if (k == 0) invl[w][h] = 1.f / l;
  }
  __syncthreads();

  // ---- Phase C: a_mean; compact (amv) or LDS dense scatter (drow) ----
  { f32x4 i0v = *(f32x4*)&invl[w][0], i1v = *(f32x4*)&invl[w][4];
    for (int s = lane; s < cnt; s += 64){
      f32x4 e0 = *(f32x4*)&E[w][s][0], e1 = *(f32x4*)&E[w][s][4];
      float a = e0[0]*i0v[0] + e0[1]*i0v[1] + e0[2]*i0v[2] + e0[3]*i0v[3]
              + e1[0]*i1v[0] + e1[1]*i1v[1] + e1[2]*i1v[2] + e1[3]*i1v[3];
      a *= 0.125f;
      if (dense) drow[w][idxl[w][s]] = f2bf(a);
      else       amv[((long)(b*Nn + i))*CAP + s] = a;
    }
  }

  // ---- Phase D: PV, 2-way unrolled ----
  { const int d0 = lane * 4, h = lane >> 3;
    f32x4 acc = {0.f, 0.f, 0.f, 0.f};
    int s = 0;
    for (; s + 2 <= cnt; s += 2){
      int ja = idxl[w][s], jb = idxl[w][s+1];
      u32x2 va = *(const u32x2*)(qkv + ((long)(b*Nn + ja)) * 768 + 512 + d0);
      u32x2 vb = *(const u32x2*)(qkv + ((long)(b*Nn + jb)) * 768 + 512 + d0);
      float ea = E[w][s][h], eb = E[w][s+1][h];
      acc[0] += ea * bf2f((u16)(va[0] & 0xffff)) + eb * bf2f((u16)(vb[0] & 0xffff));
      acc[1] += ea * bf2f((u16)(va[0] >> 16))    + eb * bf2f((u16)(vb[0] >> 16));
      acc[2] += ea * bf2f((u16)(va[1] & 0xffff)) + eb * bf2f((u16)(vb[1] & 0xffff));
      acc[3] += ea * bf2f((u16)(va[1] >> 16))    + eb * bf2f((u16)(vb[1] >> 16));
    }
    if (s < cnt){
      int ja = idxl[w][s];
      u32x2 va = *(const u32x2*)(qkv + ((long)(b*Nn + ja)) * 768 + 512 + d0);
      float ea = E[w][s][h];
      acc[0] += ea * bf2f((u16)(va[0] & 0xffff));
      acc[1] += ea * bf2f((u16)(va[0] >> 16));
      acc[2] += ea * bf2f((u16)(va[1] & 0xffff));
      acc[3] += ea * bf2f((u16)(va[1] >> 16));
    }
    float nl = invl[w][h];
    u32x2 pb;
    pb[0] = (u32)f2bf(acc[0]*nl) | ((u32)f2bf(acc[1]*nl) << 16);
    pb[1] = (u32)f2bf(acc[2]*nl) | ((u32)f2bf(acc[3]*nl) << 16);
    *(u32x2*)(ob + ((long)(b*Nn + i)) * 256 + d0) = pb;
  }

  // ---- dense row flush: 4 contiguous rows = flat 8KB, coalesced 16B/lane ----
  if (dense){
    __syncthreads();
    const u32x4* src = (const u32x4*)&drow[0][0];      // 512 chunks of 8 u16
    u32x4* dst = (u32x4*)(amd + ((long)(b*Nn + i0))*1024);
    #pragma unroll
    for (int t = tid; t < 512; t += 256) dst[t] = src[t];
  }
}

// ---------------- sparse chain: dst_row[i] = sum_s wts[i][s] * rows[idx[i][s]] ----------------
template<bool OUTF32>
__global__ __launch_bounds__(256) void sp_chain(
    const float* __restrict__ wts,        // [B*N][CAP] compact weights
    const u16* __restrict__ rows,         // [B*N][1024] dense bf16 rows
    const u16* __restrict__ idxg, const int* __restrict__ cntg,
    u16* __restrict__ dstb, float* __restrict__ dstf)
{
  __shared__ u16 idxl[CAP];
  __shared__ float wl[CAP];
  const int b = blockIdx.y, i = blockIdx.x, tid = threadIdx.x;
  const int cnt = cntg[i];
  if (tid < CAP){
    idxl[tid] = idxg[(long)i*CAP + tid];
    wl[tid]   = wts[((long)(b*Nn + i))*CAP + tid];
  }
  __syncthreads();
  f32x4 acc = {0.f, 0.f, 0.f, 0.f};
  const int c0 = tid * 4;
  int s = 0;
  for (; s + 2 <= cnt; s += 2){
    int ja = idxl[s], jb = idxl[s+1];
    float ea = wl[s], eb = wl[s+1];
    u32x2 va = *(const u32x2*)(rows + ((long)(b*Nn + ja))*1024 + c0);
    u32x2 vb = *(const u32x2*)(rows + ((long)(b*Nn + jb))*1024 + c0);
    acc[0] += ea * bf2f((u16)(va[0] & 0xffff)) + eb * bf2f((u16)(vb[0] & 0xffff));
    acc[1] += ea * bf2f((u16)(va[0] >> 16))    + eb * bf2f((u16)(vb[0] >> 16));
    acc[2] += ea * bf2f((u16)(va[1] & 0xffff)) + eb * bf2f((u16)(vb[1] & 0xffff));
    acc[3] += ea * bf2f((u16)(va[1] >> 16))    + eb * bf2f((u16)(vb[1] >> 16));
  }
  if (s < cnt){
    int ja = idxl[s];
    float ea = wl[s];
    u32x2 va = *(const u32x2*)(rows + ((long)(b*Nn + ja))*1024 + c0);
    acc[0] += ea * bf2f((u16)(va[0] & 0xffff));
    acc[1] += ea * bf2f((u16)(va[0] >> 16));
    acc[2] += ea * bf2f((u16)(va[1] & 0xffff));
    acc[3] += ea * bf2f((u16)(va[1] >> 16));
  }
  if (OUTF32){
    *(f32x4*)(dstf + ((long)(b*Nn + i))*1024 + c0) = acc;
  } else {
    u32x2 pb;
    pb[0] = (u32)f2bf(acc[0]) | ((u32)f2bf(acc[1]) << 16);
    pb[1] = (u32)f2bf(acc[2]) | ((u32)f2bf(acc[3]) << 16);
    *(u32x2*)(dstb + ((long)(b*Nn + i))*1024 + c0) = pb;
  }
}

// ---------------- residual + layernorm ----------------
__global__ __launch_bounds__(256) void ln_kernel(
    const float* __restrict__ hin, const float* __restrict__ y,
    float* __restrict__ hout, u16* __restrict__ hb, float* __restrict__ outf,
    const float* __restrict__ g, const float* __restrict__ be)
{
  int row  = blockIdx.x * 4 + (threadIdx.x >> 6);
  int lane = threadIdx.x & 63;
  f32x4 v = *(const f32x4*)(hin + (long)row*Dd + lane*4)
          + *(const f32x4*)(y   + (long)row*Dd + lane*4);
  float s = v[0] + v[1] + v[2] + v[3];
  #pragma unroll
  for (int off = 32; off; off >>= 1) s += __shfl_xor(s, off, 64);
  float mu = s * (1.f/256.f);
  f32x4 d = v - mu;
  float q2 = d[0]*d[0] + d[1]*d[1] + d[2]*d[2] + d[3]*d[3];
  #pragma unroll
  for (int off = 32; off; off >>= 1) q2 += __shfl_xor(q2, off, 64);
  float rs = rsqrtf(q2 * (1.f/256.f) + 1e-5f);
  f32x4 ov;
  #pragma unroll
  for (int p = 0; p < 4; ++p)
    ov[p] = d[p] * rs * g[lane*4 + p] + be[lane*4 + p];
  *(f32x4*)(hout + (long)row*Dd + lane*4) = ov;
  if (hb){
    u32x2 pb;
    pb[0] = (u32)f2bf(ov[0]) | ((u32)f2bf(ov[1]) << 16);
    pb[1] = (u32)f2bf(ov[2]) | ((u32)f2bf(ov[3]) << 16);
    *(u32x2*)(hb + (long)row*Dd + lane*4) = pb;
  }
  if (outf)
    *(f32x4*)(outf + (long)row*Dd + lane*4) = ov;
}

extern "C" void kernel_launch(void* const* d_in, const int* in_sizes, int n_in,
                              void* d_out, int out_size, void* d_ws, size_t ws_size,
                              hipStream_t stream)
{
  (void)in_sizes; (void)n_in; (void)out_size; (void)ws_size;
  const float* x   = (const float*)d_in[0];
  const float* adj = (const float*)d_in[1];
  const float* W0  = (const float*)d_in[2];
  const float* Wq  = (const float*)d_in[3];
  const float* bq  = (const float*)d_in[4];
  const float* Wk  = (const float*)d_in[5];
  const float* bk  = (const float*)d_in[6];
  const float* Wv  = (const float*)d_in[7];
  const float* bv  = (const float*)d_in[8];
  const float* Wo  = (const float*)d_in[9];
  const float* bo  = (const float*)d_in[10];
  const float* gm  = (const float*)d_in[11];
  const float* bt  = (const float*)d_in[12];
  float* outf  = (float*)d_out;                 // f32 h region [8,1024,256]
  float* outat = outf + (long)Bb * Nn * Dd;     // f32 atten region [8,1024,1024]

  // ---- workspace (~83MB < proven 92MB) ----
  char* w = (char*)d_ws;
  u16* W0b  = (u16*)w; w += 131072;             // W0|Wq|Wk|Wv|Wo contiguous (conv_w5)
  u16* Wqb  = (u16*)w; w += 4*393216;
  float* bqkv = (float*)w; w += 9216;           // [3][768]
  u32* bitsg = (u32*)w; w += 131072;
  u16* idxg  = (u16*)w; w += 1024*CAP*2;        // 192KB
  int* cntg  = (int*)w; w += 4096;
  u16* xb  = (u16*)w; w += 4194304;
  u16* hb  = (u16*)w; w += 4194304;
  u16* qkv = (u16*)w; w += (long)Bb*Nn*768*2;   // 12MB
  u16* ob  = (u16*)w; w += 4194304;
  float* hbuf = (float*)w; w += 8388608;
  float* ybuf = (float*)w; w += 8388608;
  float* amv1 = (float*)w; w += (long)Bb*Nn*CAP*4;  // 3MB
  float* amv2 = (float*)w; w += (long)Bb*Nn*CAP*4;  // 3MB
  u16* P1   = (u16*)w; w += 16777216;           // [8][1024][1024] bf16
  u16* am0d = (u16*)w; w += 16777216;           // dense am0 [8][1024][1024] bf16

  dim3 blk(256);
  f32_to_bf16<<<2048, blk, 0, stream>>>(x, xb, 2097152);
  conv_w5<<<833, blk, 0, stream>>>(W0, Wq, Wk, Wv, Wo, W0b, bq, bk, bv, bqkv);
  adj_to_bits<<<128, blk, 0, stream>>>(adj, bitsg);
  nbr_build<<<4, blk, 0, stream>>>(bitsg, idxg, cntg);

  // input projection: h = x @ W0^T  (f32 + bf16)
  gemm_bt<false,false,true,true><<<dim3(2,64,1), blk, 0, stream>>>(
      xb, 256, 0, W0b, 256, 0, hbuf, hb, 256, 0, 256, nullptr, 0, nullptr);

  for (int l = 0; l < 3; ++l){
    // fused q|k|v projection
    gemm_bt<true,false,false,true><<<dim3(2,64,3), blk, 0, stream>>>(
        hb, 256, 0, Wqb + (long)l*65536, 256, 196608,
        nullptr, qkv, 768, 256, 256, bqkv + l*768, 256, nullptr);
    // sparse attention: l0 builds dense am0d rows in-kernel (no memset)
    attn_sparse<<<dim3(256,8), blk, 0, stream>>>(
        qkv, ob, idxg, cntg,
        (l == 1 ? amv1 : amv2), am0d, (l == 0) ? 1 : 0);
    // y = o @ Wo^T + bo (f32)
    gemm_bt<true,false,true,false><<<dim3(2,64,1), blk, 0, stream>>>(
        ob, 256, 0, Wqb + (long)(3*3+l)*65536, 256, 0, ybuf, nullptr, 256, 0, 256,
        bo + l*256, 0, nullptr);
    // h = LN(h + y)
    ln_kernel<<<dim3(2048), blk, 0, stream>>>(
        hbuf, ybuf, hbuf, (l < 2 ? hb : nullptr), (l < 2 ? nullptr : outf),
        gm + l*256, bt + l*256);
    // chain: P1 = am1 @ am0d (bf16); final = am2 @ P1 (f32 -> d_out)
    if (l == 1)
      sp_chain<false><<<dim3(1024,8), blk, 0, stream>>>(
          amv1, am0d, idxg, cntg, P1, nullptr);
    if (l == 2)
      sp_chain<true><<<dim3(1024,8), blk, 0, stream>>>(
          amv2, P1, idxg, cntg, nullptr, outat);
  }
}

// Round 15
// 291.575 us; speedup vs baseline: 1.0554x; 1.0554x over previous
//
#include <hip/hip_runtime.h>

typedef unsigned short u16;
typedef unsigned int   u32;
typedef float  f32x4  __attribute__((ext_vector_type(4)));
typedef __bf16 bf16x8 __attribute__((ext_vector_type(8)));
typedef u32    u32x4  __attribute__((ext_vector_type(4)));
typedef u32    u32x2  __attribute__((ext_vector_type(2)));

#define Bb  8
#define Nn  1024
#define Dd  256
#define Hh  8
#define HDd 32
#define CAP 96

__device__ __forceinline__ float bf2f(u16 s){
  u32 u = ((u32)s) << 16; float f; __builtin_memcpy(&f, &u, 4); return f;
}
__device__ __forceinline__ u16 f2bf(float f){
  u32 u; __builtin_memcpy(&u, &f, 4);
  u = (u + 0x7fffu + ((u >> 16) & 1u)) >> 16;
  return (u16)u;
}
__device__ __forceinline__ f32x4 mfma16(bf16x8 a, bf16x8 b, f32x4 c){
  return __builtin_amdgcn_mfma_f32_16x16x32_bf16(a, b, c, 0, 0, 0);
}
__device__ __forceinline__ bf16x8 ld_bf8(const u16* p){
  u32x4 u = *(const u32x4*)p; bf16x8 r; __builtin_memcpy(&r, &u, 16); return r;
}

// ---------------- f32 -> bf16 convert ----------------
__global__ void f32_to_bf16(const float* __restrict__ src, u16* __restrict__ dst, int n){
  int i = (blockIdx.x * 256 + threadIdx.x) * 4;
  if (i < n){
    f32x4 v = *(const f32x4*)(src + i);
    u32x2 p;
    p[0] = (u32)f2bf(v[0]) | ((u32)f2bf(v[1]) << 16);
    p[1] = (u32)f2bf(v[2]) | ((u32)f2bf(v[3]) << 16);
    *(u32x2*)(dst + i) = p;
  }
}

// ---------------- fused 5-weight convert + bias concat ----------------
__global__ void conv_w5(const float* __restrict__ w0, const float* __restrict__ wq,
                        const float* __restrict__ wk, const float* __restrict__ wv,
                        const float* __restrict__ wo, u16* __restrict__ dst,
                        const float* __restrict__ bq, const float* __restrict__ bk,
                        const float* __restrict__ bv, float* __restrict__ bqkv){
  if (blockIdx.x == 832){
    int t = threadIdx.x;
    for (int l = 0; l < 3; ++l){
      bqkv[l*768 +       t] = bq[l*256 + t];
      bqkv[l*768 + 256 + t] = bk[l*256 + t];
      bqkv[l*768 + 512 + t] = bv[l*256 + t];
    }
    return;
  }
  int g4 = (blockIdx.x * 256 + threadIdx.x) * 4;
  const float* src;
  int off;
  if (g4 < 65536){ src = w0; off = g4; }
  else {
    int g = g4 - 65536;
    int sec = g / 196608; off = g - sec * 196608;
    src = (sec == 0 ? wq : sec == 1 ? wk : sec == 2 ? wv : wo);
  }
  f32x4 v = *(const f32x4*)(src + off);
  u32x2 p;
  p[0] = (u32)f2bf(v[0]) | ((u32)f2bf(v[1]) << 16);
  p[1] = (u32)f2bf(v[2]) | ((u32)f2bf(v[3]) << 16);
  *(u32x2*)(dst + g4) = p;
}

// ---------------- adj -> bitmask ----------------
__global__ void adj_to_bits(const float* __restrict__ adj, u32* __restrict__ bits){
  int w = blockIdx.x * 256 + threadIdx.x;        // word over [1024][32]
  const float* p = adj + (long)w * 32;
  u32 m = 0;
  #pragma unroll
  for (int t = 0; t < 32; t += 4){
    f32x4 v = *(const f32x4*)(p + t);
    if (v[0] != 0.f) m |= 1u << (t+0);
    if (v[1] != 0.f) m |= 1u << (t+1);
    if (v[2] != 0.f) m |= 1u << (t+2);
    if (v[3] != 0.f) m |= 1u << (t+3);
  }
  bits[w] = m;
}

// ---------------- neighbor list build (CSR, capacity CAP) ----------------
__global__ __launch_bounds__(256) void nbr_build(const u32* __restrict__ bits,
                                                 u16* __restrict__ idx, int* __restrict__ cnt){
  int i = blockIdx.x * 256 + threadIdx.x;        // grid 4
  int c = 0;
  for (int w = 0; w < 32; ++w){
    u32 wd = bits[i*32 + w];
    while (wd){
      int bi = __ffs(wd) - 1; wd &= wd - 1;
      if (c < CAP) idx[(long)i*CAP + c] = (u16)(w*32 + bi);
      ++c;
    }
  }
  cnt[i] = (c < CAP) ? c : CAP;
}

// ---------------- MFMA GEMM (VALIDATED R4-R14) ----------------
template<bool HBC, bool HBR, bool OF, bool OB>
__global__ __launch_bounds__(256,2) void gemm_bt(
    const u16* __restrict__ A, int lda, long sA,
    const u16* __restrict__ Bt, int ldb, long sB,
    float* __restrict__ Cf, u16* __restrict__ Cb, int ldc, long sC,
    int K, const float* __restrict__ bc, long sbc, const float* __restrict__ br)
{
  __shared__ u16 As[128][40];
  __shared__ u16 Bs[128][40];
  const int bz = blockIdx.z;
  const u16* Ap = A + (long)bz * sA;
  const u16* Bp = Bt + (long)bz * sB;
  const long co = (long)bz * sC;
  const int m0 = blockIdx.y * 128, n0 = blockIdx.x * 128;
  const int tid = threadIdx.x, wave = tid >> 6, lane = tid & 63;
  const int arow = lane & 15, agrp = lane >> 4;
  const int wr = (wave >> 1) * 64, wc = (wave & 1) * 64;
  const int srow = tid >> 1, sch = (tid & 1) * 16;
  const u16* ga = Ap + (long)(m0 + srow) * lda + sch;
  const u16* gb = Bp + (long)(n0 + srow) * ldb + sch;
  f32x4 acc[4][4] = {};
  for (int kb = 0; kb < K; kb += 32){
    u32x4 a0 = *(const u32x4*)ga; u32x4 a1 = *(const u32x4*)(ga + 8);
    u32x4 b0 = *(const u32x4*)gb; u32x4 b1 = *(const u32x4*)(gb + 8);
    __syncthreads();
    *(u32x4*)&As[srow][sch] = a0; *(u32x4*)&As[srow][sch + 8] = a1;
    *(u32x4*)&Bs[srow][sch] = b0; *(u32x4*)&Bs[srow][sch + 8] = b1;
    __syncthreads();
    ga += 32; gb += 32;
    bf16x8 af[4], bv[4];
    #pragma unroll
    for (int f = 0; f < 4; ++f){
      af[f] = ld_bf8(&As[wr + f*16 + arow][agrp*8]);
      bv[f] = ld_bf8(&Bs[wc + f*16 + arow][agrp*8]);
    }
    #pragma unroll
    for (int fm = 0; fm < 4; ++fm)
      #pragma unroll
      for (int fn = 0; fn < 4; ++fn)
        acc[fm][fn] = mfma16(af[fm], bv[fn], acc[fm][fn]);
  }
  #pragma unroll
  for (int fm = 0; fm < 4; ++fm){
    #pragma unroll
    for (int fn = 0; fn < 4; ++fn){
      int j = n0 + wc + fn*16 + arow;
      float badd = 0.f;
      if (HBC) badd = bc[(long)bz*sbc + j];
      #pragma unroll
      for (int r = 0; r < 4; ++r){
        int i = m0 + wr + fm*16 + agrp*4 + r;
        float v = acc[fm][fn][r] + badd;
        if (HBR) v += br[i];
        long idx = co + (long)i * ldc + j;
        if (OF) Cf[idx] = v;
        if (OB) Cb[idx] = f2bf(v);
      }
    }
  }
}

// ---------------- sparse attention v8: DENSE is a template param (LDS only when needed) ----------------
// grid (256, 8): i0 = blockIdx.x*4, b = blockIdx.y
template<int DENSE>
__global__ __launch_bounds__(256) void attn_sparse(
    const u16* __restrict__ qkv,          // [B*N][768] bf16: q|k|v
    u16* __restrict__ ob,                 // [B*N][256] bf16
    const u16* __restrict__ idxg, const int* __restrict__ cntg,
    float* __restrict__ amv,              // compact dst (DENSE==0)
    u16* __restrict__ amd)                // dense dst [B*N][1024] bf16 (DENSE==1)
{
  __shared__ float qs[4][256];            // q rows, pre-scaled f32
  __shared__ float E[4][CAP][8];          // raw scores -> unnormalized exp
  __shared__ float invl[4][8];            // per-(row,head) 1/sum
  __shared__ u16   idxl[4][CAP];
  __shared__ int   cntl[4];
  __shared__ u16   drow[DENSE ? 4*1024 : 4];  // dense a_mean rows (DENSE only)
  const int b = blockIdx.y, i0 = blockIdx.x * 4;
  const int tid = threadIdx.x, w = tid >> 6, lane = tid & 63;
  const float SCALE = 0.17677669529663687f;   // 1/sqrt(32)

  { int e = tid * 4, rr = e >> 8, c = e & 255;
    u32x2 uv = *(const u32x2*)(qkv + ((long)(b*Nn + i0 + rr)) * 768 + c);
    qs[rr][c+0] = SCALE * bf2f((u16)(uv[0] & 0xffff));
    qs[rr][c+1] = SCALE * bf2f((u16)(uv[0] >> 16));
    qs[rr][c+2] = SCALE * bf2f((u16)(uv[1] & 0xffff));
    qs[rr][c+3] = SCALE * bf2f((u16)(uv[1] >> 16)); }
  for (int s = tid; s < 4*CAP; s += 256){
    int rr = s / CAP, ss = s - rr*CAP;
    idxl[rr][ss] = idxg[(long)(i0 + rr)*CAP + ss];
  }
  if (tid < 4) cntl[tid] = cntg[i0 + tid];
  if (DENSE){                              // zero dense rows (2048 dwords)
    u32* dz = (u32*)&drow[0];
    #pragma unroll
    for (int t = tid; t < 2048; t += 256) dz[t] = 0;
  }
  __syncthreads();

  const int i = i0 + w;
  const int cnt = cntl[w];

  // ---- Phase A: coalesced 512B K-row reads; 8-lane group reduce; 2-way unroll ----
  { const f32x4 qreg = *(const f32x4*)&qs[w][lane*4];
    const int h = lane >> 3;
    int s = 0;
    for (; s + 2 <= cnt; s += 2){
      int ja = idxl[w][s], jb = idxl[w][s+1];
      u32x2 ka = *(const u32x2*)(qkv + ((long)(b*Nn + ja))*768 + 256 + lane*4);
      u32x2 kb = *(const u32x2*)(qkv + ((long)(b*Nn + jb))*768 + 256 + lane*4);
      float pa = qreg[0]*bf2f((u16)(ka[0]&0xffff)) + qreg[1]*bf2f((u16)(ka[0]>>16))
               + qreg[2]*bf2f((u16)(ka[1]&0xffff)) + qreg[3]*bf2f((u16)(ka[1]>>16));
      float pb = qreg[0]*bf2f((u16)(kb[0]&0xffff)) + qreg[1]*bf2f((u16)(kb[0]>>16))
               + qreg[2]*bf2f((u16)(kb[1]&0xffff)) + qreg[3]*bf2f((u16)(kb[1]>>16));
      pa += __shfl_xor(pa, 1, 64); pa += __shfl_xor(pa, 2, 64); pa += __shfl_xor(pa, 4, 64);
      pb += __shfl_xor(pb, 1, 64); pb += __shfl_xor(pb, 2, 64); pb += __shfl_xor(pb, 4, 64);
      if ((lane & 7) == 0){ E[w][s][h] = pa; E[w][s+1][h] = pb; }
    }
    if (s < cnt){
      int ja = idxl[w][s];
      u32x2 ka = *(const u32x2*)(qkv + ((long)(b*Nn + ja))*768 + 256 + lane*4);
      float pa = qreg[0]*bf2f((u16)(ka[0]&0xffff)) + qreg[1]*bf2f((u16)(ka[0]>>16))
               + qreg[2]*bf2f((u16)(ka[1]&0xffff)) + qreg[3]*bf2f((u16)(ka[1]>>16));
      pa += __shfl_xor(pa, 1, 64); pa += __shfl_xor(pa, 2, 64); pa += __shfl_xor(pa, 4, 64);
      if ((lane & 7) == 0) E[w][s][h] = pa;
    }
  }
  __syncthreads();

  // ---- Phase B: per-head max/sum; lane = h*8+k owns slots s==k (mod 8) ----
  { const int h = lane >> 3, k = lane & 7;
    float m = -3.0e38f;
    for (int s = k; s < cnt; s += 8) m = fmaxf(m, E[w][s][h]);
    m = fmaxf(m, __shfl_xor(m, 1, 64));
    m = fmaxf(m, __shfl_xor(m, 2, 64));
    m = fmaxf(m, __shfl_xor(m, 4, 64));
    float l = 0.f;
    for (int s = k; s < cnt; s += 8){
      float e = __expf(E[w][s][h] - m);
      E[w][s][h] = e; l += e;
    }
    l += __shfl_xor(l, 1, 64);
    l += __shfl_xor(l, 2, 64);
    l += __shfl_xor(l, 4, 64);
    if (k == 0) invl[w][h] = 1.f / l;
  }
  __syncthreads();

  // ---- Phase C: a_mean; compact (amv) or LDS dense scatter (drow) ----
  { f32x4 i0v = *(f32x4*)&invl[w][0], i1v = *(f32x4*)&invl[w][4];
    for (int s = lane; s < cnt; s += 64){
      f32x4 e0 = *(f32x4*)&E[w][s][0], e1 = *(f32x4*)&E[w][s][4];
      float a = e0[0]*i0v[0] + e0[1]*i0v[1] + e0[2]*i0v[2] + e0[3]*i0v[3]
              + e1[0]*i1v[0] + e1[1]*i1v[1] + e1[2]*i1v[2] + e1[3]*i1v[3];
      a *= 0.125f;
      if (DENSE) drow[w*1024 + idxl[w][s]] = f2bf(a);
      else       amv[((long)(b*Nn + i))*CAP + s] = a;
    }
  }

  // ---- Phase D: PV, 2-way unrolled ----
  { const int d0 = lane * 4, h = lane >> 3;
    f32x4 acc = {0.f, 0.f, 0.f, 0.f};
    int s = 0;
    for (; s + 2 <= cnt; s += 2){
      int ja = idxl[w][s], jb = idxl[w][s+1];
      u32x2 va = *(const u32x2*)(qkv + ((long)(b*Nn + ja)) * 768 + 512 + d0);
      u32x2 vb = *(const u32x2*)(qkv + ((long)(b*Nn + jb)) * 768 + 512 + d0);
      float ea = E[w][s][h], eb = E[w][s+1][h];
      acc[0] += ea * bf2f((u16)(va[0] & 0xffff)) + eb * bf2f((u16)(vb[0] & 0xffff));
      acc[1] += ea * bf2f((u16)(va[0] >> 16))    + eb * bf2f((u16)(vb[0] >> 16));
      acc[2] += ea * bf2f((u16)(va[1] & 0xffff)) + eb * bf2f((u16)(vb[1] & 0xffff));
      acc[3] += ea * bf2f((u16)(va[1] >> 16))    + eb * bf2f((u16)(vb[1] >> 16));
    }
    if (s < cnt){
      int ja = idxl[w][s];
      u32x2 va = *(const u32x2*)(qkv + ((long)(b*Nn + ja)) * 768 + 512 + d0);
      float ea = E[w][s][h];
      acc[0] += ea * bf2f((u16)(va[0] & 0xffff));
      acc[1] += ea * bf2f((u16)(va[0] >> 16));
      acc[2] += ea * bf2f((u16)(va[1] & 0xffff));
      acc[3] += ea * bf2f((u16)(va[1] >> 16));
    }
    float nl = invl[w][h];
    u32x2 pb;
    pb[0] = (u32)f2bf(acc[0]*nl) | ((u32)f2bf(acc[1]*nl) << 16);
    pb[1] = (u32)f2bf(acc[2]*nl) | ((u32)f2bf(acc[3]*nl) << 16);
    *(u32x2*)(ob + ((long)(b*Nn + i)) * 256 + d0) = pb;
  }

  // ---- dense row flush: 4 contiguous rows = flat 8KB, coalesced 16B/lane ----
  if (DENSE){
    __syncthreads();
    const u32x4* src = (const u32x4*)&drow[0];         // 512 chunks of 8 u16
    u32x4* dst = (u32x4*)(amd + ((long)(b*Nn + i0))*1024);
    #pragma unroll
    for (int t = tid; t < 512; t += 256) dst[t] = src[t];
  }
}

// ---------------- sparse chain: dst_row[i] = sum_s wts[i][s] * rows[idx[i][s]] ----------------
template<bool OUTF32>
__global__ __launch_bounds__(256) void sp_chain(
    const float* __restrict__ wts,        // [B*N][CAP] compact weights
    const u16* __restrict__ rows,         // [B*N][1024] dense bf16 rows
    const u16* __restrict__ idxg, const int* __restrict__ cntg,
    u16* __restrict__ dstb, float* __restrict__ dstf)
{
  __shared__ u16 idxl[CAP];
  __shared__ float wl[CAP];
  const int b = blockIdx.y, i = blockIdx.x, tid = threadIdx.x;
  const int cnt = cntg[i];
  if (tid < CAP){
    idxl[tid] = idxg[(long)i*CAP + tid];
    wl[tid]   = wts[((long)(b*Nn + i))*CAP + tid];
  }
  __syncthreads();
  f32x4 acc = {0.f, 0.f, 0.f, 0.f};
  const int c0 = tid * 4;
  int s = 0;
  for (; s + 2 <= cnt; s += 2){
    int ja = idxl[s], jb = idxl[s+1];
    float ea = wl[s], eb = wl[s+1];
    u32x2 va = *(const u32x2*)(rows + ((long)(b*Nn + ja))*1024 + c0);
    u32x2 vb = *(const u32x2*)(rows + ((long)(b*Nn + jb))*1024 + c0);
    acc[0] += ea * bf2f((u16)(va[0] & 0xffff)) + eb * bf2f((u16)(vb[0] & 0xffff));
    acc[1] += ea * bf2f((u16)(va[0] >> 16))    + eb * bf2f((u16)(vb[0] >> 16));
    acc[2] += ea * bf2f((u16)(va[1] & 0xffff)) + eb * bf2f((u16)(vb[1] & 0xffff));
    acc[3] += ea * bf2f((u16)(va[1] >> 16))    + eb * bf2f((u16)(vb[1] >> 16));
  }
  if (s < cnt){
    int ja = idxl[s];
    float ea = wl[s];
    u32x2 va = *(const u32x2*)(rows + ((long)(b*Nn + ja))*1024 + c0);
    acc[0] += ea * bf2f((u16)(va[0] & 0xffff));
    acc[1] += ea * bf2f((u16)(va[0] >> 16));
    acc[2] += ea * bf2f((u16)(va[1] & 0xffff));
    acc[3] += ea * bf2f((u16)(va[1] >> 16));
  }
  if (OUTF32){
    *(f32x4*)(dstf + ((long)(b*Nn + i))*1024 + c0) = acc;
  } else {
    u32x2 pb;
    pb[0] = (u32)f2bf(acc[0]) | ((u32)f2bf(acc[1]) << 16);
    pb[1] = (u32)f2bf(acc[2]) | ((u32)f2bf(acc[3]) << 16);
    *(u32x2*)(dstb + ((long)(b*Nn + i))*1024 + c0) = pb;
  }
}

// ---------------- residual + layernorm ----------------
__global__ __launch_bounds__(256) void ln_kernel(
    const float* __restrict__ hin, const float* __restrict__ y,
    float* __restrict__ hout, u16* __restrict__ hb, float* __restrict__ outf,
    const float* __restrict__ g, const float* __restrict__ be)
{
  int row  = blockIdx.x * 4 + (threadIdx.x >> 6);
  int lane = threadIdx.x & 63;
  f32x4 v = *(const f32x4*)(hin + (long)row*Dd + lane*4)
          + *(const f32x4*)(y   + (long)row*Dd + lane*4);
  float s = v[0] + v[1] + v[2] + v[3];
  #pragma unroll
  for (int off = 32; off; off >>= 1) s += __shfl_xor(s, off, 64);
  float mu = s * (1.f/256.f);
  f32x4 d = v - mu;
  float q2 = d[0]*d[0] + d[1]*d[1] + d[2]*d[2] + d[3]*d[3];
  #pragma unroll
  for (int off = 32; off; off >>= 1) q2 += __shfl_xor(q2, off, 64);
  float rs = rsqrtf(q2 * (1.f/256.f) + 1e-5f);
  f32x4 ov;
  #pragma unroll
  for (int p = 0; p < 4; ++p)
    ov[p] = d[p] * rs * g[lane*4 + p] + be[lane*4 + p];
  *(f32x4*)(hout + (long)row*Dd + lane*4) = ov;
  if (hb){
    u32x2 pb;
    pb[0] = (u32)f2bf(ov[0]) | ((u32)f2bf(ov[1]) << 16);
    pb[1] = (u32)f2bf(ov[2]) | ((u32)f2bf(ov[3]) << 16);
    *(u32x2*)(hb + (long)row*Dd + lane*4) = pb;
  }
  if (outf)
    *(f32x4*)(outf + (long)row*Dd + lane*4) = ov;
}

extern "C" void kernel_launch(void* const* d_in, const int* in_sizes, int n_in,
                              void* d_out, int out_size, void* d_ws, size_t ws_size,
                              hipStream_t stream)
{
  (void)in_sizes; (void)n_in; (void)out_size; (void)ws_size;
  const float* x   = (const float*)d_in[0];
  const float* adj = (const float*)d_in[1];
  const float* W0  = (const float*)d_in[2];
  const float* Wq  = (const float*)d_in[3];
  const float* bq  = (const float*)d_in[4];
  const float* Wk  = (const float*)d_in[5];
  const float* bk  = (const float*)d_in[6];
  const float* Wv  = (const float*)d_in[7];
  const float* bv  = (const float*)d_in[8];
  const float* Wo  = (const float*)d_in[9];
  const float* bo  = (const float*)d_in[10];
  const float* gm  = (const float*)d_in[11];
  const float* bt  = (const float*)d_in[12];
  float* outf  = (float*)d_out;                 // f32 h region [8,1024,256]
  float* outat = outf + (long)Bb * Nn * Dd;     // f32 atten region [8,1024,1024]

  // ---- workspace (~83MB < proven 92MB) ----
  char* w = (char*)d_ws;
  u16* W0b  = (u16*)w; w += 131072;             // W0|Wq|Wk|Wv|Wo contiguous (conv_w5)
  u16* Wqb  = (u16*)w; w += 4*393216;
  float* bqkv = (float*)w; w += 9216;           // [3][768]
  u32* bitsg = (u32*)w; w += 131072;
  u16* idxg  = (u16*)w; w += 1024*CAP*2;        // 192KB
  int* cntg  = (int*)w; w += 4096;
  u16* xb  = (u16*)w; w += 4194304;
  u16* hb  = (u16*)w; w += 4194304;
  u16* qkv = (u16*)w; w += (long)Bb*Nn*768*2;   // 12MB
  u16* ob  = (u16*)w; w += 4194304;
  float* hbuf = (float*)w; w += 8388608;
  float* ybuf = (float*)w; w += 8388608;
  float* amv1 = (float*)w; w += (long)Bb*Nn*CAP*4;  // 3MB
  float* amv2 = (float*)w; w += (long)Bb*Nn*CAP*4;  // 3MB
  u16* P1   = (u16*)w; w += 16777216;           // [8][1024][1024] bf16
  u16* am0d = (u16*)w; w += 16777216;           // dense am0 [8][1024][1024] bf16

  dim3 blk(256);
  f32_to_bf16<<<2048, blk, 0, stream>>>(x, xb, 2097152);
  conv_w5<<<833, blk, 0, stream>>>(W0, Wq, Wk, Wv, Wo, W0b, bq, bk, bv, bqkv);
  adj_to_bits<<<128, blk, 0, stream>>>(adj, bitsg);
  nbr_build<<<4, blk, 0, stream>>>(bitsg, idxg, cntg);

  // input projection: h = x @ W0^T  (f32 + bf16)
  gemm_bt<false,false,true,true><<<dim3(2,64,1), blk, 0, stream>>>(
      xb, 256, 0, W0b, 256, 0, hbuf, hb, 256, 0, 256, nullptr, 0, nullptr);

  for (int l = 0; l < 3; ++l){
    // fused q|k|v projection
    gemm_bt<true,false,false,true><<<dim3(2,64,3), blk, 0, stream>>>(
        hb, 256, 0, Wqb + (long)l*65536, 256, 196608,
        nullptr, qkv, 768, 256, 256, bqkv + l*768, 256, nullptr);
    // sparse attention: l0 builds dense am0d rows in-kernel; l1/l2 compact
    if (l == 0)
      attn_sparse<1><<<dim3(256,8), blk, 0, stream>>>(
          qkv, ob, idxg, cntg, nullptr, am0d);
    else
      attn_sparse<0><<<dim3(256,8), blk, 0, stream>>>(
          qkv, ob, idxg, cntg, (l == 1 ? amv1 : amv2), nullptr);
    // y = o @ Wo^T + bo (f32)
    gemm_bt<true,false,true,false><<<dim3(2,64,1), blk, 0, stream>>>(
        ob, 256, 0, Wqb + (long)(3*3+l)*65536, 256, 0, ybuf, nullptr, 256, 0, 256,
        bo + l*256, 0, nullptr);
    // h = LN(h + y)
    ln_kernel<<<dim3(2048), blk, 0, stream>>>(
        hbuf, ybuf, hbuf, (l < 2 ? hb : nullptr), (l < 2 ? nullptr : outf),
        gm + l*256, bt + l*256);
    // chain: P1 = am1 @ am0d (bf16); final = am2 @ P1 (f32 -> d_out)
    if (l == 1)
      sp_chain<false><<<dim3(1024,8), blk, 0, stream>>>(
          amv1, am0d, idxg, cntg, P1, nullptr);
    if (l == 2)
      sp_chain<true><<<dim3(1024,8), blk, 0, stream>>>(
          amv2, P1, idxg, cntg, nullptr, outat);
  }
}

// Round 16
// 262.802 us; speedup vs baseline: 1.1710x; 1.1095x over previous
//
#include <hip/hip_runtime.h>

typedef unsigned short u16;
typedef unsigned int   u32;
typedef float  f32x4  __attribute__((ext_vector_type(4)));
typedef __bf16 bf16x8 __attribute__((ext_vector_type(8)));
typedef u32    u32x4  __attribute__((ext_vector_type(4)));
typedef u32    u32x2  __attribute__((ext_vector_type(2)));

#define Bb  8
#define Nn  1024
#define Dd  256
#define Hh  8
#define HDd 32
#define CAP 96

__device__ __forceinline__ float bf2f(u16 s){
  u32 u = ((u32)s) << 16; float f; __builtin_memcpy(&f, &u, 4); return f;
}
__device__ __forceinline__ u16 f2bf(float f){
  u32 u; __builtin_memcpy(&u, &f, 4);
  u = (u + 0x7fffu + ((u >> 16) & 1u)) >> 16;
  return (u16)u;
}
__device__ __forceinline__ f32x4 mfma16(bf16x8 a, bf16x8 b, f32x4 c){
  return __builtin_amdgcn_mfma_f32_16x16x32_bf16(a, b, c, 0, 0, 0);
}
__device__ __forceinline__ bf16x8 ld_bf8(const u16* p){
  u32x4 u = *(const u32x4*)p; bf16x8 r; __builtin_memcpy(&r, &u, 16); return r;
}

// ---------------- f32 -> bf16 convert ----------------
__global__ void f32_to_bf16(const float* __restrict__ src, u16* __restrict__ dst, int n){
  int i = (blockIdx.x * 256 + threadIdx.x) * 4;
  if (i < n){
    f32x4 v = *(const f32x4*)(src + i);
    u32x2 p;
    p[0] = (u32)f2bf(v[0]) | ((u32)f2bf(v[1]) << 16);
    p[1] = (u32)f2bf(v[2]) | ((u32)f2bf(v[3]) << 16);
    *(u32x2*)(dst + i) = p;
  }
}

// ---------------- fused 5-weight convert + bias concat ----------------
__global__ void conv_w5(const float* __restrict__ w0, const float* __restrict__ wq,
                        const float* __restrict__ wk, const float* __restrict__ wv,
                        const float* __restrict__ wo, u16* __restrict__ dst,
                        const float* __restrict__ bq, const float* __restrict__ bk,
                        const float* __restrict__ bv, float* __restrict__ bqkv){
  if (blockIdx.x == 832){
    int t = threadIdx.x;
    for (int l = 0; l < 3; ++l){
      bqkv[l*768 +       t] = bq[l*256 + t];
      bqkv[l*768 + 256 + t] = bk[l*256 + t];
      bqkv[l*768 + 512 + t] = bv[l*256 + t];
    }
    return;
  }
  int g4 = (blockIdx.x * 256 + threadIdx.x) * 4;
  const float* src;
  int off;
  if (g4 < 65536){ src = w0; off = g4; }
  else {
    int g = g4 - 65536;
    int sec = g / 196608; off = g - sec * 196608;
    src = (sec == 0 ? wq : sec == 1 ? wk : sec == 2 ? wv : wo);
  }
  f32x4 v = *(const f32x4*)(src + off);
  u32x2 p;
  p[0] = (u32)f2bf(v[0]) | ((u32)f2bf(v[1]) << 16);
  p[1] = (u32)f2bf(v[2]) | ((u32)f2bf(v[3]) << 16);
  *(u32x2*)(dst + g4) = p;
}

// ---------------- adj -> bitmask ----------------
__global__ void adj_to_bits(const float* __restrict__ adj, u32* __restrict__ bits){
  int w = blockIdx.x * 256 + threadIdx.x;        // word over [1024][32]
  const float* p = adj + (long)w * 32;
  u32 m = 0;
  #pragma unroll
  for (int t = 0; t < 32; t += 4){
    f32x4 v = *(const f32x4*)(p + t);
    if (v[0] != 0.f) m |= 1u << (t+0);
    if (v[1] != 0.f) m |= 1u << (t+1);
    if (v[2] != 0.f) m |= 1u << (t+2);
    if (v[3] != 0.f) m |= 1u << (t+3);
  }
  bits[w] = m;
}

// ---------------- neighbor list build (CSR, capacity CAP) ----------------
__global__ __launch_bounds__(256) void nbr_build(const u32* __restrict__ bits,
                                                 u16* __restrict__ idx, int* __restrict__ cnt){
  int i = blockIdx.x * 256 + threadIdx.x;        // grid 4
  int c = 0;
  for (int w = 0; w < 32; ++w){
    u32 wd = bits[i*32 + w];
    while (wd){
      int bi = __ffs(wd) - 1; wd &= wd - 1;
      if (c < CAP) idx[(long)i*CAP + c] = (u16)(w*32 + bi);
      ++c;
    }
  }
  cnt[i] = (c < CAP) ? c : CAP;
}

// ---------------- MFMA GEMM (VALIDATED R4-R15) ----------------
template<bool HBC, bool HBR, bool OF, bool OB>
__global__ __launch_bounds__(256,2) void gemm_bt(
    const u16* __restrict__ A, int lda, long sA,
    const u16* __restrict__ Bt, int ldb, long sB,
    float* __restrict__ Cf, u16* __restrict__ Cb, int ldc, long sC,
    int K, const float* __restrict__ bc, long sbc, const float* __restrict__ br)
{
  __shared__ u16 As[128][40];
  __shared__ u16 Bs[128][40];
  const int bz = blockIdx.z;
  const u16* Ap = A + (long)bz * sA;
  const u16* Bp = Bt + (long)bz * sB;
  const long co = (long)bz * sC;
  const int m0 = blockIdx.y * 128, n0 = blockIdx.x * 128;
  const int tid = threadIdx.x, wave = tid >> 6, lane = tid & 63;
  const int arow = lane & 15, agrp = lane >> 4;
  const int wr = (wave >> 1) * 64, wc = (wave & 1) * 64;
  const int srow = tid >> 1, sch = (tid & 1) * 16;
  const u16* ga = Ap + (long)(m0 + srow) * lda + sch;
  const u16* gb = Bp + (long)(n0 + srow) * ldb + sch;
  f32x4 acc[4][4] = {};
  for (int kb = 0; kb < K; kb += 32){
    u32x4 a0 = *(const u32x4*)ga; u32x4 a1 = *(const u32x4*)(ga + 8);
    u32x4 b0 = *(const u32x4*)gb; u32x4 b1 = *(const u32x4*)(gb + 8);
    __syncthreads();
    *(u32x4*)&As[srow][sch] = a0; *(u32x4*)&As[srow][sch + 8] = a1;
    *(u32x4*)&Bs[srow][sch] = b0; *(u32x4*)&Bs[srow][sch + 8] = b1;
    __syncthreads();
    ga += 32; gb += 32;
    bf16x8 af[4], bv[4];
    #pragma unroll
    for (int f = 0; f < 4; ++f){
      af[f] = ld_bf8(&As[wr + f*16 + arow][agrp*8]);
      bv[f] = ld_bf8(&Bs[wc + f*16 + arow][agrp*8]);
    }
    #pragma unroll
    for (int fm = 0; fm < 4; ++fm)
      #pragma unroll
      for (int fn = 0; fn < 4; ++fn)
        acc[fm][fn] = mfma16(af[fm], bv[fn], acc[fm][fn]);
  }
  #pragma unroll
  for (int fm = 0; fm < 4; ++fm){
    #pragma unroll
    for (int fn = 0; fn < 4; ++fn){
      int j = n0 + wc + fn*16 + arow;
      float badd = 0.f;
      if (HBC) badd = bc[(long)bz*sbc + j];
      #pragma unroll
      for (int r = 0; r < 4; ++r){
        int i = m0 + wr + fm*16 + agrp*4 + r;
        float v = acc[fm][fn][r] + badd;
        if (HBR) v += br[i];
        long idx = co + (long)i * ldc + j;
        if (OF) Cf[idx] = v;
        if (OB) Cb[idx] = f2bf(v);
      }
    }
  }
}

// ---------------- sparse attention v9: 2 rows/wave-iter (32-lane halves), 16B lanes ----------------
// grid (256, 8): i0 = blockIdx.x*4, b = blockIdx.y
template<int DENSE>
__global__ __launch_bounds__(256) void attn_sparse(
    const u16* __restrict__ qkv,          // [B*N][768] bf16: q|k|v
    u16* __restrict__ ob,                 // [B*N][256] bf16
    const u16* __restrict__ idxg, const int* __restrict__ cntg,
    float* __restrict__ amv,              // compact dst (DENSE==0)
    u16* __restrict__ amd)                // dense dst [B*N][1024] bf16 (DENSE==1)
{
  __shared__ float qs[4][256];            // q rows, pre-scaled f32
  __shared__ float E[4][CAP][8];          // raw scores -> unnormalized exp
  __shared__ float invl[4][8];            // per-(row,head) 1/sum
  __shared__ u16   idxl[4][CAP];
  __shared__ int   cntl[4];
  __shared__ u16   drow[DENSE ? 4*1024 : 4];  // dense a_mean rows (DENSE only)
  const int b = blockIdx.y, i0 = blockIdx.x * 4;
  const int tid = threadIdx.x, w = tid >> 6, lane = tid & 63;
  const float SCALE = 0.17677669529663687f;   // 1/sqrt(32)

  { int e = tid * 4, rr = e >> 8, c = e & 255;
    u32x2 uv = *(const u32x2*)(qkv + ((long)(b*Nn + i0 + rr)) * 768 + c);
    qs[rr][c+0] = SCALE * bf2f((u16)(uv[0] & 0xffff));
    qs[rr][c+1] = SCALE * bf2f((u16)(uv[0] >> 16));
    qs[rr][c+2] = SCALE * bf2f((u16)(uv[1] & 0xffff));
    qs[rr][c+3] = SCALE * bf2f((u16)(uv[1] >> 16)); }
  for (int s = tid; s < 4*CAP; s += 256){
    int rr = s / CAP, ss = s - rr*CAP;
    idxl[rr][ss] = idxg[(long)(i0 + rr)*CAP + ss];
  }
  if (tid < 4) cntl[tid] = cntg[i0 + tid];
  if (DENSE){                              // zero dense rows (2048 dwords)
    u32* dz = (u32*)&drow[0];
    #pragma unroll
    for (int t = tid; t < 2048; t += 256) dz[t] = 0;
  }
  __syncthreads();

  const int i = i0 + w;
  const int cnt = cntl[w];
  const int half = lane >> 5, lq = lane & 31;
  const int hh = lq >> 2;                 // head for this lane's 8-dim slice

  // ---- Phase A: 2 K-rows per wave-iter (one per half), 16B/lane, 2-way unroll ----
  { const f32x4 q0 = *(const f32x4*)&qs[w][lq*8];
    const f32x4 q1 = *(const f32x4*)&qs[w][lq*8 + 4];
    int s = 0;
    for (; s + 4 <= cnt; s += 4){
      int j0 = idxl[w][s + half], j1 = idxl[w][s + 2 + half];
      bf16x8 k0 = ld_bf8(qkv + ((long)(b*Nn + j0))*768 + 256 + lq*8);
      bf16x8 k1 = ld_bf8(qkv + ((long)(b*Nn + j1))*768 + 256 + lq*8);
      float p0 = q0[0]*(float)k0[0] + q0[1]*(float)k0[1] + q0[2]*(float)k0[2] + q0[3]*(float)k0[3]
               + q1[0]*(float)k0[4] + q1[1]*(float)k0[5] + q1[2]*(float)k0[6] + q1[3]*(float)k0[7];
      float p1 = q0[0]*(float)k1[0] + q0[1]*(float)k1[1] + q0[2]*(float)k1[2] + q0[3]*(float)k1[3]
               + q1[0]*(float)k1[4] + q1[1]*(float)k1[5] + q1[2]*(float)k1[6] + q1[3]*(float)k1[7];
      p0 += __shfl_xor(p0, 1, 64); p0 += __shfl_xor(p0, 2, 64);
      p1 += __shfl_xor(p1, 1, 64); p1 += __shfl_xor(p1, 2, 64);
      if ((lq & 3) == 0){ E[w][s + half][hh] = p0; E[w][s + 2 + half][hh] = p1; }
    }
    for (; s + 2 <= cnt; s += 2){
      int j0 = idxl[w][s + half];
      bf16x8 k0 = ld_bf8(qkv + ((long)(b*Nn + j0))*768 + 256 + lq*8);
      float p0 = q0[0]*(float)k0[0] + q0[1]*(float)k0[1] + q0[2]*(float)k0[2] + q0[3]*(float)k0[3]
               + q1[0]*(float)k0[4] + q1[1]*(float)k0[5] + q1[2]*(float)k0[6] + q1[3]*(float)k0[7];
      p0 += __shfl_xor(p0, 1, 64); p0 += __shfl_xor(p0, 2, 64);
      if ((lq & 3) == 0) E[w][s + half][hh] = p0;
    }
    if (s < cnt){                          // last row: both halves compute, half 0 writes
      int j0 = idxl[w][s];
      bf16x8 k0 = ld_bf8(qkv + ((long)(b*Nn + j0))*768 + 256 + lq*8);
      float p0 = q0[0]*(float)k0[0] + q0[1]*(float)k0[1] + q0[2]*(float)k0[2] + q0[3]*(float)k0[3]
               + q1[0]*(float)k0[4] + q1[1]*(float)k0[5] + q1[2]*(float)k0[6] + q1[3]*(float)k0[7];
      p0 += __shfl_xor(p0, 1, 64); p0 += __shfl_xor(p0, 2, 64);
      if (half == 0 && (lq & 3) == 0) E[w][s][hh] = p0;
    }
  }
  __syncthreads();

  // ---- Phase B: per-head max/sum; lane = h*8+k owns slots s==k (mod 8) ----
  { const int h = lane >> 3, k = lane & 7;
    float m = -3.0e38f;
    for (int s = k; s < cnt; s += 8) m = fmaxf(m, E[w][s][h]);
    m = fmaxf(m, __shfl_xor(m, 1, 64));
    m = fmaxf(m, __shfl_xor(m, 2, 64));
    m = fmaxf(m, __shfl_xor(m, 4, 64));
    float l = 0.f;
    for (int s = k; s < cnt; s += 8){
      float e = __expf(E[w][s][h] - m);
      E[w][s][h] = e; l += e;
    }
    l += __shfl_xor(l, 1, 64);
    l += __shfl_xor(l, 2, 64);
    l += __shfl_xor(l, 4, 64);
    if (k == 0) invl[w][h] = 1.f / l;
  }
  __syncthreads();

  // ---- Phase C: a_mean; compact (amv) or LDS dense scatter (drow) ----
  { f32x4 i0v = *(f32x4*)&invl[w][0], i1v = *(f32x4*)&invl[w][4];
    for (int s = lane; s < cnt; s += 64){
      f32x4 e0 = *(f32x4*)&E[w][s][0], e1 = *(f32x4*)&E[w][s][4];
      float a = e0[0]*i0v[0] + e0[1]*i0v[1] + e0[2]*i0v[2] + e0[3]*i0v[3]
              + e1[0]*i1v[0] + e1[1]*i1v[1] + e1[2]*i1v[2] + e1[3]*i1v[3];
      a *= 0.125f;
      if (DENSE) drow[w*1024 + idxl[w][s]] = f2bf(a);
      else       amv[((long)(b*Nn + i))*CAP + s] = a;
    }
  }

  // ---- Phase D: PV; 2 V-rows per wave-iter (parity halves), 16B/lane, 2-way unroll ----
  { f32x4 a0 = {0.f,0.f,0.f,0.f}, a1 = {0.f,0.f,0.f,0.f};
    int s = 0;
    for (; s + 4 <= cnt; s += 4){
      int j0 = idxl[w][s + half], j1 = idxl[w][s + 2 + half];
      bf16x8 v0 = ld_bf8(qkv + ((long)(b*Nn + j0))*768 + 512 + lq*8);
      bf16x8 v1 = ld_bf8(qkv + ((long)(b*Nn + j1))*768 + 512 + lq*8);
      float e0 = E[w][s + half][hh], e1 = E[w][s + 2 + half][hh];
      a0[0] += e0*(float)v0[0] + e1*(float)v1[0];
      a0[1] += e0*(float)v0[1] + e1*(float)v1[1];
      a0[2] += e0*(float)v0[2] + e1*(float)v1[2];
      a0[3] += e0*(float)v0[3] + e1*(float)v1[3];
      a1[0] += e0*(float)v0[4] + e1*(float)v1[4];
      a1[1] += e0*(float)v0[5] + e1*(float)v1[5];
      a1[2] += e0*(float)v0[6] + e1*(float)v1[6];
      a1[3] += e0*(float)v0[7] + e1*(float)v1[7];
    }
    for (; s + 2 <= cnt; s += 2){
      int j0 = idxl[w][s + half];
      bf16x8 v0 = ld_bf8(qkv + ((long)(b*Nn + j0))*768 + 512 + lq*8);
      float e0 = E[w][s + half][hh];
      a0[0] += e0*(float)v0[0]; a0[1] += e0*(float)v0[1];
      a0[2] += e0*(float)v0[2]; a0[3] += e0*(float)v0[3];
      a1[0] += e0*(float)v0[4]; a1[1] += e0*(float)v0[5];
      a1[2] += e0*(float)v0[6]; a1[3] += e0*(float)v0[7];
    }
    if (s < cnt && half == 0){             // last row: half 0 only (avoid double count)
      int j0 = idxl[w][s];
      bf16x8 v0 = ld_bf8(qkv + ((long)(b*Nn + j0))*768 + 512 + lq*8);
      float e0 = E[w][s][hh];
      a0[0] += e0*(float)v0[0]; a0[1] += e0*(float)v0[1];
      a0[2] += e0*(float)v0[2]; a0[3] += e0*(float)v0[3];
      a1[0] += e0*(float)v0[4]; a1[1] += e0*(float)v0[5];
      a1[2] += e0*(float)v0[6]; a1[3] += e0*(float)v0[7];
    }
    // combine parity halves (lane <-> lane+32)
    #pragma unroll
    for (int p = 0; p < 4; ++p){
      a0[p] += __shfl_xor(a0[p], 32, 64);
      a1[p] += __shfl_xor(a1[p], 32, 64);
    }
    if (half == 0){
      float nl = invl[w][hh];
      u32x4 pb;
      pb[0] = (u32)f2bf(a0[0]*nl) | ((u32)f2bf(a0[1]*nl) << 16);
      pb[1] = (u32)f2bf(a0[2]*nl) | ((u32)f2bf(a0[3]*nl) << 16);
      pb[2] = (u32)f2bf(a1[0]*nl) | ((u32)f2bf(a1[1]*nl) << 16);
      pb[3] = (u32)f2bf(a1[2]*nl) | ((u32)f2bf(a1[3]*nl) << 16);
      *(u32x4*)(ob + ((long)(b*Nn + i)) * 256 + lq*8) = pb;
    }
  }

  // ---- dense row flush: 4 contiguous rows = flat 8KB, coalesced 16B/lane ----
  if (DENSE){
    __syncthreads();
    const u32x4* src = (const u32x4*)&drow[0];         // 512 chunks of 8 u16
    u32x4* dst = (u32x4*)(amd + ((long)(b*Nn + i0))*1024);
    #pragma unroll
    for (int t = tid; t < 512; t += 256) dst[t] = src[t];
  }
}

// ---------------- sparse chain: dst_row[i] = sum_s wts[i][s] * rows[idx[i][s]] ----------------
template<bool OUTF32>
__global__ __launch_bounds__(256) void sp_chain(
    const float* __restrict__ wts,        // [B*N][CAP] compact weights
    const u16* __restrict__ rows,         // [B*N][1024] dense bf16 rows
    const u16* __restrict__ idxg, const int* __restrict__ cntg,
    u16* __restrict__ dstb, float* __restrict__ dstf)
{
  __shared__ u16 idxl[CAP];
  __shared__ float wl[CAP];
  const int b = blockIdx.y, i = blockIdx.x, tid = threadIdx.x;
  const int cnt = cntg[i];
  if (tid < CAP){
    idxl[tid] = idxg[(long)i*CAP + tid];
    wl[tid]   = wts[((long)(b*Nn + i))*CAP + tid];
  }
  __syncthreads();
  f32x4 acc = {0.f, 0.f, 0.f, 0.f};
  const int c0 = tid * 4;
  int s = 0;
  for (; s + 2 <= cnt; s += 2){
    int ja = idxl[s], jb = idxl[s+1];
    float ea = wl[s], eb = wl[s+1];
    u32x2 va = *(const u32x2*)(rows + ((long)(b*Nn + ja))*1024 + c0);
    u32x2 vb = *(const u32x2*)(rows + ((long)(b*Nn + jb))*1024 + c0);
    acc[0] += ea * bf2f((u16)(va[0] & 0xffff)) + eb * bf2f((u16)(vb[0] & 0xffff));
    acc[1] += ea * bf2f((u16)(va[0] >> 16))    + eb * bf2f((u16)(vb[0] >> 16));
    acc[2] += ea * bf2f((u16)(va[1] & 0xffff)) + eb * bf2f((u16)(vb[1] & 0xffff));
    acc[3] += ea * bf2f((u16)(va[1] >> 16))    + eb * bf2f((u16)(vb[1] >> 16));
  }
  if (s < cnt){
    int ja = idxl[s];
    float ea = wl[s];
    u32x2 va = *(const u32x2*)(rows + ((long)(b*Nn + ja))*1024 + c0);
    acc[0] += ea * bf2f((u16)(va[0] & 0xffff));
    acc[1] += ea * bf2f((u16)(va[0] >> 16));
    acc[2] += ea * bf2f((u16)(va[1] & 0xffff));
    acc[3] += ea * bf2f((u16)(va[1] >> 16));
  }
  if (OUTF32){
    *(f32x4*)(dstf + ((long)(b*Nn + i))*1024 + c0) = acc;
  } else {
    u32x2 pb;
    pb[0] = (u32)f2bf(acc[0]) | ((u32)f2bf(acc[1]) << 16);
    pb[1] = (u32)f2bf(acc[2]) | ((u32)f2bf(acc[3]) << 16);
    *(u32x2*)(dstb + ((long)(b*Nn + i))*1024 + c0) = pb;
  }
}

// ---------------- residual + layernorm ----------------
__global__ __launch_bounds__(256) void ln_kernel(
    const float* __restrict__ hin, const float* __restrict__ y,
    float* __restrict__ hout, u16* __restrict__ hb, float* __restrict__ outf,
    const float* __restrict__ g, const float* __restrict__ be)
{
  int row  = blockIdx.x * 4 + (threadIdx.x >> 6);
  int lane = threadIdx.x & 63;
  f32x4 v = *(const f32x4*)(hin + (long)row*Dd + lane*4)
          + *(const f32x4*)(y   + (long)row*Dd + lane*4);
  float s = v[0] + v[1] + v[2] + v[3];
  #pragma unroll
  for (int off = 32; off; off >>= 1) s += __shfl_xor(s, off, 64);
  float mu = s * (1.f/256.f);
  f32x4 d = v - mu;
  float q2 = d[0]*d[0] + d[1]*d[1] + d[2]*d[2] + d[3]*d[3];
  #pragma unroll
  for (int off = 32; off; off >>= 1) q2 += __shfl_xor(q2, off, 64);
  float rs = rsqrtf(q2 * (1.f/256.f) + 1e-5f);
  f32x4 ov;
  #pragma unroll
  for (int p = 0; p < 4; ++p)
    ov[p] = d[p] * rs * g[lane*4 + p] + be[lane*4 + p];
  *(f32x4*)(hout + (long)row*Dd + lane*4) = ov;
  if (hb){
    u32x2 pb;
    pb[0] = (u32)f2bf(ov[0]) | ((u32)f2bf(ov[1]) << 16);
    pb[1] = (u32)f2bf(ov[2]) | ((u32)f2bf(ov[3]) << 16);
    *(u32x2*)(hb + (long)row*Dd + lane*4) = pb;
  }
  if (outf)
    *(f32x4*)(outf + (long)row*Dd + lane*4) = ov;
}

extern "C" void kernel_launch(void* const* d_in, const int* in_sizes, int n_in,
                              void* d_out, int out_size, void* d_ws, size_t ws_size,
                              hipStream_t stream)
{
  (void)in_sizes; (void)n_in; (void)out_size; (void)ws_size;
  const float* x   = (const float*)d_in[0];
  const float* adj = (const float*)d_in[1];
  const float* W0  = (const float*)d_in[2];
  const float* Wq  = (const float*)d_in[3];
  const float* bq  = (const float*)d_in[4];
  const float* Wk  = (const float*)d_in[5];
  const float* bk  = (const float*)d_in[6];
  const float* Wv  = (const float*)d_in[7];
  const float* bv  = (const float*)d_in[8];
  const float* Wo  = (const float*)d_in[9];
  const float* bo  = (const float*)d_in[10];
  const float* gm  = (const float*)d_in[11];
  const float* bt  = (const float*)d_in[12];
  float* outf  = (float*)d_out;                 // f32 h region [8,1024,256]
  float* outat = outf + (long)Bb * Nn * Dd;     // f32 atten region [8,1024,1024]

  // ---- workspace (~83MB < proven 92MB) ----
  char* w = (char*)d_ws;
  u16* W0b  = (u16*)w; w += 131072;             // W0|Wq|Wk|Wv|Wo contiguous (conv_w5)
  u16* Wqb  = (u16*)w; w += 4*393216;
  float* bqkv = (float*)w; w += 9216;           // [3][768]
  u32* bitsg = (u32*)w; w += 131072;
  u16* idxg  = (u16*)w; w += 1024*CAP*2;        // 192KB
  int* cntg  = (int*)w; w += 4096;
  u16* xb  = (u16*)w; w += 4194304;
  u16* hb  = (u16*)w; w += 4194304;
  u16* qkv = (u16*)w; w += (long)Bb*Nn*768*2;   // 12MB
  u16* ob  = (u16*)w; w += 4194304;
  float* hbuf = (float*)w; w += 8388608;
  float* ybuf = (float*)w; w += 8388608;
  float* amv1 = (float*)w; w += (long)Bb*Nn*CAP*4;  // 3MB
  float* amv2 = (float*)w; w += (long)Bb*Nn*CAP*4;  // 3MB
  u16* P1   = (u16*)w; w += 16777216;           // [8][1024][1024] bf16
  u16* am0d = (u16*)w; w += 16777216;           // dense am0 [8][1024][1024] bf16

  dim3 blk(256);
  f32_to_bf16<<<2048, blk, 0, stream>>>(x, xb, 2097152);
  conv_w5<<<833, blk, 0, stream>>>(W0, Wq, Wk, Wv, Wo, W0b, bq, bk, bv, bqkv);
  adj_to_bits<<<128, blk, 0, stream>>>(adj, bitsg);
  nbr_build<<<4, blk, 0, stream>>>(bitsg, idxg, cntg);

  // input projection: h = x @ W0^T  (f32 + bf16)
  gemm_bt<false,false,true,true><<<dim3(2,64,1), blk, 0, stream>>>(
      xb, 256, 0, W0b, 256, 0, hbuf, hb, 256, 0, 256, nullptr, 0, nullptr);

  for (int l = 0; l < 3; ++l){
    // fused q|k|v projection
    gemm_bt<true,false,false,true><<<dim3(2,64,3), blk, 0, stream>>>(
        hb, 256, 0, Wqb + (long)l*65536, 256, 196608,
        nullptr, qkv, 768, 256, 256, bqkv + l*768, 256, nullptr);
    // sparse attention: l0 builds dense am0d rows in-kernel; l1/l2 compact
    if (l == 0)
      attn_sparse<1><<<dim3(256,8), blk, 0, stream>>>(
          qkv, ob, idxg, cntg, nullptr, am0d);
    else
      attn_sparse<0><<<dim3(256,8), blk, 0, stream>>>(
          qkv, ob, idxg, cntg, (l == 1 ? amv1 : amv2), nullptr);
    // y = o @ Wo^T + bo (f32)
    gemm_bt<true,false,true,false><<<dim3(2,64,1), blk, 0, stream>>>(
        ob, 256, 0, Wqb + (long)(3*3+l)*65536, 256, 0, ybuf, nullptr, 256, 0, 256,
        bo + l*256, 0, nullptr);
    // h = LN(h + y)
    ln_kernel<<<dim3(2048), blk, 0, stream>>>(
        hbuf, ybuf, hbuf, (l < 2 ? hb : nullptr), (l < 2 ? nullptr : outf),
        gm + l*256, bt + l*256);
    // chain: P1 = am1 @ am0d (bf16); final = am2 @ P1 (f32 -> d_out)
    if (l == 1)
      sp_chain<false><<<dim3(1024,8), blk, 0, stream>>>(
          amv1, am0d, idxg, cntg, P1, nullptr);
    if (l == 2)
      sp_chain<true><<<dim3(1024,8), blk, 0, stream>>>(
          amv2, P1, idxg, cntg, nullptr, outat);
  }
}

// Round 17
// 256.949 us; speedup vs baseline: 1.1977x; 1.0228x over previous
//
#include <hip/hip_runtime.h>

typedef unsigned short u16;
typedef unsigned int   u32;
typedef float  f32x4  __attribute__((ext_vector_type(4)));
typedef __bf16 bf16x8 __attribute__((ext_vector_type(8)));
typedef u32    u32x4  __attribute__((ext_vector_type(4)));
typedef u32    u32x2  __attribute__((ext_vector_type(2)));

#define Bb  8
#define Nn  1024
#define Dd  256
#define Hh  8
#define HDd 32
#define CAP 96

__device__ __forceinline__ float bf2f(u16 s){
  u32 u = ((u32)s) << 16; float f; __builtin_memcpy(&f, &u, 4); return f;
}
__device__ __forceinline__ u16 f2bf(float f){
  u32 u; __builtin_memcpy(&u, &f, 4);
  u = (u + 0x7fffu + ((u >> 16) & 1u)) >> 16;
  return (u16)u;
}
__device__ __forceinline__ f32x4 mfma16(bf16x8 a, bf16x8 b, f32x4 c){
  return __builtin_amdgcn_mfma_f32_16x16x32_bf16(a, b, c, 0, 0, 0);
}
__device__ __forceinline__ bf16x8 ld_bf8(const u16* p){
  u32x4 u = *(const u32x4*)p; bf16x8 r; __builtin_memcpy(&r, &u, 16); return r;
}

// ---------------- f32 -> bf16 convert ----------------
__global__ void f32_to_bf16(const float* __restrict__ src, u16* __restrict__ dst, int n){
  int i = (blockIdx.x * 256 + threadIdx.x) * 4;
  if (i < n){
    f32x4 v = *(const f32x4*)(src + i);
    u32x2 p;
    p[0] = (u32)f2bf(v[0]) | ((u32)f2bf(v[1]) << 16);
    p[1] = (u32)f2bf(v[2]) | ((u32)f2bf(v[3]) << 16);
    *(u32x2*)(dst + i) = p;
  }
}

// ---------------- fused 5-weight convert + bias concat ----------------
__global__ void conv_w5(const float* __restrict__ w0, const float* __restrict__ wq,
                        const float* __restrict__ wk, const float* __restrict__ wv,
                        const float* __restrict__ wo, u16* __restrict__ dst,
                        const float* __restrict__ bq, const float* __restrict__ bk,
                        const float* __restrict__ bv, float* __restrict__ bqkv){
  if (blockIdx.x == 832){
    int t = threadIdx.x;
    for (int l = 0; l < 3; ++l){
      bqkv[l*768 +       t] = bq[l*256 + t];
      bqkv[l*768 + 256 + t] = bk[l*256 + t];
      bqkv[l*768 + 512 + t] = bv[l*256 + t];
    }
    return;
  }
  int g4 = (blockIdx.x * 256 + threadIdx.x) * 4;
  const float* src;
  int off;
  if (g4 < 65536){ src = w0; off = g4; }
  else {
    int g = g4 - 65536;
    int sec = g / 196608; off = g - sec * 196608;
    src = (sec == 0 ? wq : sec == 1 ? wk : sec == 2 ? wv : wo);
  }
  f32x4 v = *(const f32x4*)(src + off);
  u32x2 p;
  p[0] = (u32)f2bf(v[0]) | ((u32)f2bf(v[1]) << 16);
  p[1] = (u32)f2bf(v[2]) | ((u32)f2bf(v[3]) << 16);
  *(u32x2*)(dst + g4) = p;
}

// ---------------- adj -> bitmask ----------------
__global__ void adj_to_bits(const float* __restrict__ adj, u32* __restrict__ bits){
  int w = blockIdx.x * 256 + threadIdx.x;        // word over [1024][32]
  const float* p = adj + (long)w * 32;
  u32 m = 0;
  #pragma unroll
  for (int t = 0; t < 32; t += 4){
    f32x4 v = *(const f32x4*)(p + t);
    if (v[0] != 0.f) m |= 1u << (t+0);
    if (v[1] != 0.f) m |= 1u << (t+1);
    if (v[2] != 0.f) m |= 1u << (t+2);
    if (v[3] != 0.f) m |= 1u << (t+3);
  }
  bits[w] = m;
}

// ---------------- neighbor list build (CSR, capacity CAP) ----------------
__global__ __launch_bounds__(256) void nbr_build(const u32* __restrict__ bits,
                                                 u16* __restrict__ idx, int* __restrict__ cnt){
  int i = blockIdx.x * 256 + threadIdx.x;        // grid 4
  int c = 0;
  for (int w = 0; w < 32; ++w){
    u32 wd = bits[i*32 + w];
    while (wd){
      int bi = __ffs(wd) - 1; wd &= wd - 1;
      if (c < CAP) idx[(long)i*CAP + c] = (u16)(w*32 + bi);
      ++c;
    }
  }
  cnt[i] = (c < CAP) ? c : CAP;
}

// ---------------- MFMA GEMM (VALIDATED R4-R16) ----------------
template<bool HBC, bool HBR, bool OF, bool OB>
__global__ __launch_bounds__(256,2) void gemm_bt(
    const u16* __restrict__ A, int lda, long sA,
    const u16* __restrict__ Bt, int ldb, long sB,
    float* __restrict__ Cf, u16* __restrict__ Cb, int ldc, long sC,
    int K, const float* __restrict__ bc, long sbc, const float* __restrict__ br)
{
  __shared__ u16 As[128][40];
  __shared__ u16 Bs[128][40];
  const int bz = blockIdx.z;
  const u16* Ap = A + (long)bz * sA;
  const u16* Bp = Bt + (long)bz * sB;
  const long co = (long)bz * sC;
  const int m0 = blockIdx.y * 128, n0 = blockIdx.x * 128;
  const int tid = threadIdx.x, wave = tid >> 6, lane = tid & 63;
  const int arow = lane & 15, agrp = lane >> 4;
  const int wr = (wave >> 1) * 64, wc = (wave & 1) * 64;
  const int srow = tid >> 1, sch = (tid & 1) * 16;
  const u16* ga = Ap + (long)(m0 + srow) * lda + sch;
  const u16* gb = Bp + (long)(n0 + srow) * ldb + sch;
  f32x4 acc[4][4] = {};
  for (int kb = 0; kb < K; kb += 32){
    u32x4 a0 = *(const u32x4*)ga; u32x4 a1 = *(const u32x4*)(ga + 8);
    u32x4 b0 = *(const u32x4*)gb; u32x4 b1 = *(const u32x4*)(gb + 8);
    __syncthreads();
    *(u32x4*)&As[srow][sch] = a0; *(u32x4*)&As[srow][sch + 8] = a1;
    *(u32x4*)&Bs[srow][sch] = b0; *(u32x4*)&Bs[srow][sch + 8] = b1;
    __syncthreads();
    ga += 32; gb += 32;
    bf16x8 af[4], bv[4];
    #pragma unroll
    for (int f = 0; f < 4; ++f){
      af[f] = ld_bf8(&As[wr + f*16 + arow][agrp*8]);
      bv[f] = ld_bf8(&Bs[wc + f*16 + arow][agrp*8]);
    }
    #pragma unroll
    for (int fm = 0; fm < 4; ++fm)
      #pragma unroll
      for (int fn = 0; fn < 4; ++fn)
        acc[fm][fn] = mfma16(af[fm], bv[fn], acc[fm][fn]);
  }
  #pragma unroll
  for (int fm = 0; fm < 4; ++fm){
    #pragma unroll
    for (int fn = 0; fn < 4; ++fn){
      int j = n0 + wc + fn*16 + arow;
      float badd = 0.f;
      if (HBC) badd = bc[(long)bz*sbc + j];
      #pragma unroll
      for (int r = 0; r < 4; ++r){
        int i = m0 + wr + fm*16 + agrp*4 + r;
        float v = acc[fm][fn][r] + badd;
        if (HBR) v += br[i];
        long idx = co + (long)i * ldc + j;
        if (OF) Cf[idx] = v;
        if (OB) Cb[idx] = f2bf(v);
      }
    }
  }
}

// ---------------- sparse attention v10: v9 + XCD-batch affinity (1D grid, b = bid&7) ----------------
// grid (2048): b = bid&7 (-> same XCD under round-robin), i0 = (bid>>3)*4
template<int DENSE>
__global__ __launch_bounds__(256) void attn_sparse(
    const u16* __restrict__ qkv,          // [B*N][768] bf16: q|k|v
    u16* __restrict__ ob,                 // [B*N][256] bf16
    const u16* __restrict__ idxg, const int* __restrict__ cntg,
    float* __restrict__ amv,              // compact dst (DENSE==0)
    u16* __restrict__ amd)                // dense dst [B*N][1024] bf16 (DENSE==1)
{
  __shared__ float qs[4][256];            // q rows, pre-scaled f32
  __shared__ float E[4][CAP][8];          // raw scores -> unnormalized exp
  __shared__ float invl[4][8];            // per-(row,head) 1/sum
  __shared__ u16   idxl[4][CAP];
  __shared__ int   cntl[4];
  __shared__ u16   drow[DENSE ? 4*1024 : 4];  // dense a_mean rows (DENSE only)
  const int bid = blockIdx.x;
  const int b = bid & 7, i0 = (bid >> 3) * 4;
  const int tid = threadIdx.x, w = tid >> 6, lane = tid & 63;
  const float SCALE = 0.17677669529663687f;   // 1/sqrt(32)

  { int e = tid * 4, rr = e >> 8, c = e & 255;
    u32x2 uv = *(const u32x2*)(qkv + ((long)(b*Nn + i0 + rr)) * 768 + c);
    qs[rr][c+0] = SCALE * bf2f((u16)(uv[0] & 0xffff));
    qs[rr][c+1] = SCALE * bf2f((u16)(uv[0] >> 16));
    qs[rr][c+2] = SCALE * bf2f((u16)(uv[1] & 0xffff));
    qs[rr][c+3] = SCALE * bf2f((u16)(uv[1] >> 16)); }
  for (int s = tid; s < 4*CAP; s += 256){
    int rr = s / CAP, ss = s - rr*CAP;
    idxl[rr][ss] = idxg[(long)(i0 + rr)*CAP + ss];
  }
  if (tid < 4) cntl[tid] = cntg[i0 + tid];
  if (DENSE){                              // zero dense rows (2048 dwords)
    u32* dz = (u32*)&drow[0];
    #pragma unroll
    for (int t = tid; t < 2048; t += 256) dz[t] = 0;
  }
  __syncthreads();

  const int i = i0 + w;
  const int cnt = cntl[w];
  const int half = lane >> 5, lq = lane & 31;
  const int hh = lq >> 2;                 // head for this lane's 8-dim slice

  // ---- Phase A: 2 K-rows per wave-iter (one per half), 16B/lane, 2-way unroll ----
  { const f32x4 q0 = *(const f32x4*)&qs[w][lq*8];
    const f32x4 q1 = *(const f32x4*)&qs[w][lq*8 + 4];
    int s = 0;
    for (; s + 4 <= cnt; s += 4){
      int j0 = idxl[w][s + half], j1 = idxl[w][s + 2 + half];
      bf16x8 k0 = ld_bf8(qkv + ((long)(b*Nn + j0))*768 + 256 + lq*8);
      bf16x8 k1 = ld_bf8(qkv + ((long)(b*Nn + j1))*768 + 256 + lq*8);
      float p0 = q0[0]*(float)k0[0] + q0[1]*(float)k0[1] + q0[2]*(float)k0[2] + q0[3]*(float)k0[3]
               + q1[0]*(float)k0[4] + q1[1]*(float)k0[5] + q1[2]*(float)k0[6] + q1[3]*(float)k0[7];
      float p1 = q0[0]*(float)k1[0] + q0[1]*(float)k1[1] + q0[2]*(float)k1[2] + q0[3]*(float)k1[3]
               + q1[0]*(float)k1[4] + q1[1]*(float)k1[5] + q1[2]*(float)k1[6] + q1[3]*(float)k1[7];
      p0 += __shfl_xor(p0, 1, 64); p0 += __shfl_xor(p0, 2, 64);
      p1 += __shfl_xor(p1, 1, 64); p1 += __shfl_xor(p1, 2, 64);
      if ((lq & 3) == 0){ E[w][s + half][hh] = p0; E[w][s + 2 + half][hh] = p1; }
    }
    for (; s + 2 <= cnt; s += 2){
      int j0 = idxl[w][s + half];
      bf16x8 k0 = ld_bf8(qkv + ((long)(b*Nn + j0))*768 + 256 + lq*8);
      float p0 = q0[0]*(float)k0[0] + q0[1]*(float)k0[1] + q0[2]*(float)k0[2] + q0[3]*(float)k0[3]
               + q1[0]*(float)k0[4] + q1[1]*(float)k0[5] + q1[2]*(float)k0[6] + q1[3]*(float)k0[7];
      p0 += __shfl_xor(p0, 1, 64); p0 += __shfl_xor(p0, 2, 64);
      if ((lq & 3) == 0) E[w][s + half][hh] = p0;
    }
    if (s < cnt){                          // last row: both halves compute, half 0 writes
      int j0 = idxl[w][s];
      bf16x8 k0 = ld_bf8(qkv + ((long)(b*Nn + j0))*768 + 256 + lq*8);
      float p0 = q0[0]*(float)k0[0] + q0[1]*(float)k0[1] + q0[2]*(float)k0[2] + q0[3]*(float)k0[3]
               + q1[0]*(float)k0[4] + q1[1]*(float)k0[5] + q1[2]*(float)k0[6] + q1[3]*(float)k0[7];
      p0 += __shfl_xor(p0, 1, 64); p0 += __shfl_xor(p0, 2, 64);
      if (half == 0 && (lq & 3) == 0) E[w][s][hh] = p0;
    }
  }
  __syncthreads();

  // ---- Phase B: per-head max/sum; lane = h*8+k owns slots s==k (mod 8) ----
  { const int h = lane >> 3, k = lane & 7;
    float m = -3.0e38f;
    for (int s = k; s < cnt; s += 8) m = fmaxf(m, E[w][s][h]);
    m = fmaxf(m, __shfl_xor(m, 1, 64));
    m = fmaxf(m, __shfl_xor(m, 2, 64));
    m = fmaxf(m, __shfl_xor(m, 4, 64));
    float l = 0.f;
    for (int s = k; s < cnt; s += 8){
      float e = __expf(E[w][s][h] - m);
      E[w][s][h] = e; l += e;
    }
    l += __shfl_xor(l, 1, 64);
    l += __shfl_xor(l, 2, 64);
    l += __shfl_xor(l, 4, 64);
    if (k == 0) invl[w][h] = 1.f / l;
  }
  __syncthreads();

  // ---- Phase C: a_mean; compact (amv) or LDS dense scatter (drow) ----
  { f32x4 i0v = *(f32x4*)&invl[w][0], i1v = *(f32x4*)&invl[w][4];
    for (int s = lane; s < cnt; s += 64){
      f32x4 e0 = *(f32x4*)&E[w][s][0], e1 = *(f32x4*)&E[w][s][4];
      float a = e0[0]*i0v[0] + e0[1]*i0v[1] + e0[2]*i0v[2] + e0[3]*i0v[3]
              + e1[0]*i1v[0] + e1[1]*i1v[1] + e1[2]*i1v[2] + e1[3]*i1v[3];
      a *= 0.125f;
      if (DENSE) drow[w*1024 + idxl[w][s]] = f2bf(a);
      else       amv[((long)(b*Nn + i))*CAP + s] = a;
    }
  }

  // ---- Phase D: PV; 2 V-rows per wave-iter (parity halves), 16B/lane, 2-way unroll ----
  { f32x4 a0 = {0.f,0.f,0.f,0.f}, a1 = {0.f,0.f,0.f,0.f};
    int s = 0;
    for (; s + 4 <= cnt; s += 4){
      int j0 = idxl[w][s + half], j1 = idxl[w][s + 2 + half];
      bf16x8 v0 = ld_bf8(qkv + ((long)(b*Nn + j0))*768 + 512 + lq*8);
      bf16x8 v1 = ld_bf8(qkv + ((long)(b*Nn + j1))*768 + 512 + lq*8);
      float e0 = E[w][s + half][hh], e1 = E[w][s + 2 + half][hh];
      a0[0] += e0*(float)v0[0] + e1*(float)v1[0];
      a0[1] += e0*(float)v0[1] + e1*(float)v1[1];
      a0[2] += e0*(float)v0[2] + e1*(float)v1[2];
      a0[3] += e0*(float)v0[3] + e1*(float)v1[3];
      a1[0] += e0*(float)v0[4] + e1*(float)v1[4];
      a1[1] += e0*(float)v0[5] + e1*(float)v1[5];
      a1[2] += e0*(float)v0[6] + e1*(float)v1[6];
      a1[3] += e0*(float)v0[7] + e1*(float)v1[7];
    }
    for (; s + 2 <= cnt; s += 2){
      int j0 = idxl[w][s + half];
      bf16x8 v0 = ld_bf8(qkv + ((long)(b*Nn + j0))*768 + 512 + lq*8);
      float e0 = E[w][s + half][hh];
      a0[0] += e0*(float)v0[0]; a0[1] += e0*(float)v0[1];
      a0[2] += e0*(float)v0[2]; a0[3] += e0*(float)v0[3];
      a1[0] += e0*(float)v0[4]; a1[1] += e0*(float)v0[5];
      a1[2] += e0*(float)v0[6]; a1[3] += e0*(float)v0[7];
    }
    if (s < cnt && half == 0){             // last row: half 0 only (avoid double count)
      int j0 = idxl[w][s];
      bf16x8 v0 = ld_bf8(qkv + ((long)(b*Nn + j0))*768 + 512 + lq*8);
      float e0 = E[w][s][hh];
      a0[0] += e0*(float)v0[0]; a0[1] += e0*(float)v0[1];
      a0[2] += e0*(float)v0[2]; a0[3] += e0*(float)v0[3];
      a1[0] += e0*(float)v0[4]; a1[1] += e0*(float)v0[5];
      a1[2] += e0*(float)v0[6]; a1[3] += e0*(float)v0[7];
    }
    // combine parity halves (lane <-> lane+32)
    #pragma unroll
    for (int p = 0; p < 4; ++p){
      a0[p] += __shfl_xor(a0[p], 32, 64);
      a1[p] += __shfl_xor(a1[p], 32, 64);
    }
    if (half == 0){
      float nl = invl[w][hh];
      u32x4 pb;
      pb[0] = (u32)f2bf(a0[0]*nl) | ((u32)f2bf(a0[1]*nl) << 16);
      pb[1] = (u32)f2bf(a0[2]*nl) | ((u32)f2bf(a0[3]*nl) << 16);
      pb[2] = (u32)f2bf(a1[0]*nl) | ((u32)f2bf(a1[1]*nl) << 16);
      pb[3] = (u32)f2bf(a1[2]*nl) | ((u32)f2bf(a1[3]*nl) << 16);
      *(u32x4*)(ob + ((long)(b*Nn + i)) * 256 + lq*8) = pb;
    }
  }

  // ---- dense row flush: 4 contiguous rows = flat 8KB, coalesced 16B/lane ----
  if (DENSE){
    __syncthreads();
    const u32x4* src = (const u32x4*)&drow[0];         // 512 chunks of 8 u16
    u32x4* dst = (u32x4*)(amd + ((long)(b*Nn + i0))*1024);
    #pragma unroll
    for (int t = tid; t < 512; t += 256) dst[t] = src[t];
  }
}

// ---------------- sparse chain: dst_row[i] = sum_s wts[i][s] * rows[idx[i][s]] ----------------
// grid (8192): b = bid&7 (XCD affinity), i = bid>>3
template<bool OUTF32>
__global__ __launch_bounds__(256) void sp_chain(
    const float* __restrict__ wts,        // [B*N][CAP] compact weights
    const u16* __restrict__ rows,         // [B*N][1024] dense bf16 rows
    const u16* __restrict__ idxg, const int* __restrict__ cntg,
    u16* __restrict__ dstb, float* __restrict__ dstf)
{
  __shared__ u16 idxl[CAP];
  __shared__ float wl[CAP];
  const int bid = blockIdx.x;
  const int b = bid & 7, i = bid >> 3;
  const int tid = threadIdx.x;
  const int cnt = cntg[i];
  if (tid < CAP){
    idxl[tid] = idxg[(long)i*CAP + tid];
    wl[tid]   = wts[((long)(b*Nn + i))*CAP + tid];
  }
  __syncthreads();
  f32x4 acc = {0.f, 0.f, 0.f, 0.f};
  const int c0 = tid * 4;
  int s = 0;
  for (; s + 2 <= cnt; s += 2){
    int ja = idxl[s], jb = idxl[s+1];
    float ea = wl[s], eb = wl[s+1];
    u32x2 va = *(const u32x2*)(rows + ((long)(b*Nn + ja))*1024 + c0);
    u32x2 vb = *(const u32x2*)(rows + ((long)(b*Nn + jb))*1024 + c0);
    acc[0] += ea * bf2f((u16)(va[0] & 0xffff)) + eb * bf2f((u16)(vb[0] & 0xffff));
    acc[1] += ea * bf2f((u16)(va[0] >> 16))    + eb * bf2f((u16)(vb[0] >> 16));
    acc[2] += ea * bf2f((u16)(va[1] & 0xffff)) + eb * bf2f((u16)(vb[1] & 0xffff));
    acc[3] += ea * bf2f((u16)(va[1] >> 16))    + eb * bf2f((u16)(vb[1] >> 16));
  }
  if (s < cnt){
    int ja = idxl[s];
    float ea = wl[s];
    u32x2 va = *(const u32x2*)(rows + ((long)(b*Nn + ja))*1024 + c0);
    acc[0] += ea * bf2f((u16)(va[0] & 0xffff));
    acc[1] += ea * bf2f((u16)(va[0] >> 16));
    acc[2] += ea * bf2f((u16)(va[1] & 0xffff));
    acc[3] += ea * bf2f((u16)(va[1] >> 16));
  }
  if (OUTF32){
    *(f32x4*)(dstf + ((long)(b*Nn + i))*1024 + c0) = acc;
  } else {
    u32x2 pb;
    pb[0] = (u32)f2bf(acc[0]) | ((u32)f2bf(acc[1]) << 16);
    pb[1] = (u32)f2bf(acc[2]) | ((u32)f2bf(acc[3]) << 16);
    *(u32x2*)(dstb + ((long)(b*Nn + i))*1024 + c0) = pb;
  }
}

// ---------------- residual + layernorm ----------------
__global__ __launch_bounds__(256) void ln_kernel(
    const float* __restrict__ hin, const float* __restrict__ y,
    float* __restrict__ hout, u16* __restrict__ hb, float* __restrict__ outf,
    const float* __restrict__ g, const float* __restrict__ be)
{
  int row  = blockIdx.x * 4 + (threadIdx.x >> 6);
  int lane = threadIdx.x & 63;
  f32x4 v = *(const f32x4*)(hin + (long)row*Dd + lane*4)
          + *(const f32x4*)(y   + (long)row*Dd + lane*4);
  float s = v[0] + v[1] + v[2] + v[3];
  #pragma unroll
  for (int off = 32; off; off >>= 1) s += __shfl_xor(s, off, 64);
  float mu = s * (1.f/256.f);
  f32x4 d = v - mu;
  float q2 = d[0]*d[0] + d[1]*d[1] + d[2]*d[2] + d[3]*d[3];
  #pragma unroll
  for (int off = 32; off; off >>= 1) q2 += __shfl_xor(q2, off, 64);
  float rs = rsqrtf(q2 * (1.f/256.f) + 1e-5f);
  f32x4 ov;
  #pragma unroll
  for (int p = 0; p < 4; ++p)
    ov[p] = d[p] * rs * g[lane*4 + p] + be[lane*4 + p];
  *(f32x4*)(hout + (long)row*Dd + lane*4) = ov;
  if (hb){
    u32x2 pb;
    pb[0] = (u32)f2bf(ov[0]) | ((u32)f2bf(ov[1]) << 16);
    pb[1] = (u32)f2bf(ov[2]) | ((u32)f2bf(ov[3]) << 16);
    *(u32x2*)(hb + (long)row*Dd + lane*4) = pb;
  }
  if (outf)
    *(f32x4*)(outf + (long)row*Dd + lane*4) = ov;
}

extern "C" void kernel_launch(void* const* d_in, const int* in_sizes, int n_in,
                              void* d_out, int out_size, void* d_ws, size_t ws_size,
                              hipStream_t stream)
{
  (void)in_sizes; (void)n_in; (void)out_size; (void)ws_size;
  const float* x   = (const float*)d_in[0];
  const float* adj = (const float*)d_in[1];
  const float* W0  = (const float*)d_in[2];
  const float* Wq  = (const float*)d_in[3];
  const float* bq  = (const float*)d_in[4];
  const float* Wk  = (const float*)d_in[5];
  const float* bk  = (const float*)d_in[6];
  const float* Wv  = (const float*)d_in[7];
  const float* bv  = (const float*)d_in[8];
  const float* Wo  = (const float*)d_in[9];
  const float* bo  = (const float*)d_in[10];
  const float* gm  = (const float*)d_in[11];
  const float* bt  = (const float*)d_in[12];
  float* outf  = (float*)d_out;                 // f32 h region [8,1024,256]
  float* outat = outf + (long)Bb * Nn * Dd;     // f32 atten region [8,1024,1024]

  // ---- workspace (~83MB < proven 92MB) ----
  char* w = (char*)d_ws;
  u16* W0b  = (u16*)w; w += 131072;             // W0|Wq|Wk|Wv|Wo contiguous (conv_w5)
  u16* Wqb  = (u16*)w; w += 4*393216;
  float* bqkv = (float*)w; w += 9216;           // [3][768]
  u32* bitsg = (u32*)w; w += 131072;
  u16* idxg  = (u16*)w; w += 1024*CAP*2;        // 192KB
  int* cntg  = (int*)w; w += 4096;
  u16* xb  = (u16*)w; w += 4194304;
  u16* hb  = (u16*)w; w += 4194304;
  u16* qkv = (u16*)w; w += (long)Bb*Nn*768*2;   // 12MB
  u16* ob  = (u16*)w; w += 4194304;
  float* hbuf = (float*)w; w += 8388608;
  float* ybuf = (float*)w; w += 8388608;
  float* amv1 = (float*)w; w += (long)Bb*Nn*CAP*4;  // 3MB
  float* amv2 = (float*)w; w += (long)Bb*Nn*CAP*4;  // 3MB
  u16* P1   = (u16*)w; w += 16777216;           // [8][1024][1024] bf16
  u16* am0d = (u16*)w; w += 16777216;           // dense am0 [8][1024][1024] bf16

  dim3 blk(256);
  f32_to_bf16<<<2048, blk, 0, stream>>>(x, xb, 2097152);
  conv_w5<<<833, blk, 0, stream>>>(W0, Wq, Wk, Wv, Wo, W0b, bq, bk, bv, bqkv);
  adj_to_bits<<<128, blk, 0, stream>>>(adj, bitsg);
  nbr_build<<<4, blk, 0, stream>>>(bitsg, idxg, cntg);

  // input projection: h = x @ W0^T  (f32 + bf16)
  gemm_bt<false,false,true,true><<<dim3(2,64,1), blk, 0, stream>>>(
      xb, 256, 0, W0b, 256, 0, hbuf, hb, 256, 0, 256, nullptr, 0, nullptr);

  for (int l = 0; l < 3; ++l){
    // fused q|k|v projection
    gemm_bt<true,false,false,true><<<dim3(2,64,3), blk, 0, stream>>>(
        hb, 256, 0, Wqb + (long)l*65536, 256, 196608,
        nullptr, qkv, 768, 256, 256, bqkv + l*768, 256, nullptr);
    // sparse attention (1D grid, XCD-batch affinity): l0 dense am0d, l1/l2 compact
    if (l == 0)
      attn_sparse<1><<<dim3(2048), blk, 0, stream>>>(
          qkv, ob, idxg, cntg, nullptr, am0d);
    else
      attn_sparse<0><<<dim3(2048), blk, 0, stream>>>(
          qkv, ob, idxg, cntg, (l == 1 ? amv1 : amv2), nullptr);
    // y = o @ Wo^T + bo (f32)
    gemm_bt<true,false,true,false><<<dim3(2,64,1), blk, 0, stream>>>(
        ob, 256, 0, Wqb + (long)(3*3+l)*65536, 256, 0, ybuf, nullptr, 256, 0, 256,
        bo + l*256, 0, nullptr);
    // h = LN(h + y)
    ln_kernel<<<dim3(2048), blk, 0, stream>>>(
        hbuf, ybuf, hbuf, (l < 2 ? hb : nullptr), (l < 2 ? nullptr : outf),
        gm + l*256, bt + l*256);
    // chain: P1 = am1 @ am0d (bf16); final = am2 @ P1 (f32 -> d_out)
    if (l == 1)
      sp_chain<false><<<dim3(8192), blk, 0, stream>>>(
          amv1, am0d, idxg, cntg, P1, nullptr);
    if (l == 2)
      sp_chain<true><<<dim3(8192), blk, 0, stream>>>(
          amv2, P1, idxg, cntg, nullptr, outat);
  }
}

// Round 18
// 254.511 us; speedup vs baseline: 1.2091x; 1.0096x over previous
//
#include <hip/hip_runtime.h>

typedef unsigned short u16;
typedef unsigned int   u32;
typedef float  f32x4  __attribute__((ext_vector_type(4)));
typedef __bf16 bf16x8 __attribute__((ext_vector_type(8)));
typedef u32    u32x4  __attribute__((ext_vector_type(4)));
typedef u32    u32x2  __attribute__((ext_vector_type(2)));

#define Bb  8
#define Nn  1024
#define Dd  256
#define Hh  8
#define HDd 32
#define CAP 96

__device__ __forceinline__ float bf2f(u16 s){
  u32 u = ((u32)s) << 16; float f; __builtin_memcpy(&f, &u, 4); return f;
}
__device__ __forceinline__ u16 f2bf(float f){
  u32 u; __builtin_memcpy(&u, &f, 4);
  u = (u + 0x7fffu + ((u >> 16) & 1u)) >> 16;
  return (u16)u;
}
__device__ __forceinline__ f32x4 mfma16(bf16x8 a, bf16x8 b, f32x4 c){
  return __builtin_amdgcn_mfma_f32_16x16x32_bf16(a, b, c, 0, 0, 0);
}
__device__ __forceinline__ bf16x8 ld_bf8(const u16* p){
  u32x4 u = *(const u32x4*)p; bf16x8 r; __builtin_memcpy(&r, &u, 16); return r;
}

// ---------------- f32 -> bf16 convert ----------------
__global__ void f32_to_bf16(const float* __restrict__ src, u16* __restrict__ dst, int n){
  int i = (blockIdx.x * 256 + threadIdx.x) * 4;
  if (i < n){
    f32x4 v = *(const f32x4*)(src + i);
    u32x2 p;
    p[0] = (u32)f2bf(v[0]) | ((u32)f2bf(v[1]) << 16);
    p[1] = (u32)f2bf(v[2]) | ((u32)f2bf(v[3]) << 16);
    *(u32x2*)(dst + i) = p;
  }
}

// ---------------- fused 5-weight convert + bias concat ----------------
__global__ void conv_w5(const float* __restrict__ w0, const float* __restrict__ wq,
                        const float* __restrict__ wk, const float* __restrict__ wv,
                        const float* __restrict__ wo, u16* __restrict__ dst,
                        const float* __restrict__ bq, const float* __restrict__ bk,
                        const float* __restrict__ bv, float* __restrict__ bqkv){
  if (blockIdx.x == 832){
    int t = threadIdx.x;
    for (int l = 0; l < 3; ++l){
      bqkv[l*768 +       t] = bq[l*256 + t];
      bqkv[l*768 + 256 + t] = bk[l*256 + t];
      bqkv[l*768 + 512 + t] = bv[l*256 + t];
    }
    return;
  }
  int g4 = (blockIdx.x * 256 + threadIdx.x) * 4;
  const float* src;
  int off;
  if (g4 < 65536){ src = w0; off = g4; }
  else {
    int g = g4 - 65536;
    int sec = g / 196608; off = g - sec * 196608;
    src = (sec == 0 ? wq : sec == 1 ? wk : sec == 2 ? wv : wo);
  }
  f32x4 v = *(const f32x4*)(src + off);
  u32x2 p;
  p[0] = (u32)f2bf(v[0]) | ((u32)f2bf(v[1]) << 16);
  p[1] = (u32)f2bf(v[2]) | ((u32)f2bf(v[3]) << 16);
  *(u32x2*)(dst + g4) = p;
}

// ---------------- adj -> bitmask ----------------
__global__ void adj_to_bits(const float* __restrict__ adj, u32* __restrict__ bits){
  int w = blockIdx.x * 256 + threadIdx.x;        // word over [1024][32]
  const float* p = adj + (long)w * 32;
  u32 m = 0;
  #pragma unroll
  for (int t = 0; t < 32; t += 4){
    f32x4 v = *(const f32x4*)(p + t);
    if (v[0] != 0.f) m |= 1u << (t+0);
    if (v[1] != 0.f) m |= 1u << (t+1);
    if (v[2] != 0.f) m |= 1u << (t+2);
    if (v[3] != 0.f) m |= 1u << (t+3);
  }
  bits[w] = m;
}

// ---------------- neighbor list build (CSR, capacity CAP) ----------------
__global__ __launch_bounds__(256) void nbr_build(const u32* __restrict__ bits,
                                                 u16* __restrict__ idx, int* __restrict__ cnt){
  int i = blockIdx.x * 256 + threadIdx.x;        // grid 4
  int c = 0;
  for (int w = 0; w < 32; ++w){
    u32 wd = bits[i*32 + w];
    while (wd){
      int bi = __ffs(wd) - 1; wd &= wd - 1;
      if (c < CAP) idx[(long)i*CAP + c] = (u16)(w*32 + bi);
      ++c;
    }
  }
  cnt[i] = (c < CAP) ? c : CAP;
}

// ---------------- MFMA GEMM (VALIDATED R4-R17) ----------------
template<bool HBC, bool HBR, bool OF, bool OB>
__global__ __launch_bounds__(256,2) void gemm_bt(
    const u16* __restrict__ A, int lda, long sA,
    const u16* __restrict__ Bt, int ldb, long sB,
    float* __restrict__ Cf, u16* __restrict__ Cb, int ldc, long sC,
    int K, const float* __restrict__ bc, long sbc, const float* __restrict__ br)
{
  __shared__ u16 As[128][40];
  __shared__ u16 Bs[128][40];
  const int bz = blockIdx.z;
  const u16* Ap = A + (long)bz * sA;
  const u16* Bp = Bt + (long)bz * sB;
  const long co = (long)bz * sC;
  const int m0 = blockIdx.y * 128, n0 = blockIdx.x * 128;
  const int tid = threadIdx.x, wave = tid >> 6, lane = tid & 63;
  const int arow = lane & 15, agrp = lane >> 4;
  const int wr = (wave >> 1) * 64, wc = (wave & 1) * 64;
  const int srow = tid >> 1, sch = (tid & 1) * 16;
  const u16* ga = Ap + (long)(m0 + srow) * lda + sch;
  const u16* gb = Bp + (long)(n0 + srow) * ldb + sch;
  f32x4 acc[4][4] = {};
  for (int kb = 0; kb < K; kb += 32){
    u32x4 a0 = *(const u32x4*)ga; u32x4 a1 = *(const u32x4*)(ga + 8);
    u32x4 b0 = *(const u32x4*)gb; u32x4 b1 = *(const u32x4*)(gb + 8);
    __syncthreads();
    *(u32x4*)&As[srow][sch] = a0; *(u32x4*)&As[srow][sch + 8] = a1;
    *(u32x4*)&Bs[srow][sch] = b0; *(u32x4*)&Bs[srow][sch + 8] = b1;
    __syncthreads();
    ga += 32; gb += 32;
    bf16x8 af[4], bv[4];
    #pragma unroll
    for (int f = 0; f < 4; ++f){
      af[f] = ld_bf8(&As[wr + f*16 + arow][agrp*8]);
      bv[f] = ld_bf8(&Bs[wc + f*16 + arow][agrp*8]);
    }
    #pragma unroll
    for (int fm = 0; fm < 4; ++fm)
      #pragma unroll
      for (int fn = 0; fn < 4; ++fn)
        acc[fm][fn] = mfma16(af[fm], bv[fn], acc[fm][fn]);
  }
  #pragma unroll
  for (int fm = 0; fm < 4; ++fm){
    #pragma unroll
    for (int fn = 0; fn < 4; ++fn){
      int j = n0 + wc + fn*16 + arow;
      float badd = 0.f;
      if (HBC) badd = bc[(long)bz*sbc + j];
      #pragma unroll
      for (int r = 0; r < 4; ++r){
        int i = m0 + wr + fm*16 + agrp*4 + r;
        float v = acc[fm][fn][r] + badd;
        if (HBR) v += br[i];
        long idx = co + (long)i * ldc + j;
        if (OF) Cf[idx] = v;
        if (OB) Cb[idx] = f2bf(v);
      }
    }
  }
}

// ---------------- sparse attention v11: 4 rows/half in flight (8 gathers/wave) ----------------
// grid (2048): b = bid&7 (XCD affinity), i0 = (bid>>3)*4
template<int DENSE>
__global__ __launch_bounds__(256) void attn_sparse(
    const u16* __restrict__ qkv,          // [B*N][768] bf16: q|k|v
    u16* __restrict__ ob,                 // [B*N][256] bf16
    const u16* __restrict__ idxg, const int* __restrict__ cntg,
    float* __restrict__ amv,              // compact dst (DENSE==0)
    u16* __restrict__ amd)                // dense dst [B*N][1024] bf16 (DENSE==1)
{
  __shared__ float qs[4][256];            // q rows, pre-scaled f32
  __shared__ float E[4][CAP][8];          // raw scores -> unnormalized exp
  __shared__ float invl[4][8];            // per-(row,head) 1/sum
  __shared__ u16   idxl[4][CAP];
  __shared__ int   cntl[4];
  __shared__ u16   drow[DENSE ? 4*1024 : 4];
  const int bid = blockIdx.x;
  const int b = bid & 7, i0 = (bid >> 3) * 4;
  const int tid = threadIdx.x, w = tid >> 6, lane = tid & 63;
  const float SCALE = 0.17677669529663687f;   // 1/sqrt(32)

  { int e = tid * 4, rr = e >> 8, c = e & 255;
    u32x2 uv = *(const u32x2*)(qkv + ((long)(b*Nn + i0 + rr)) * 768 + c);
    qs[rr][c+0] = SCALE * bf2f((u16)(uv[0] & 0xffff));
    qs[rr][c+1] = SCALE * bf2f((u16)(uv[0] >> 16));
    qs[rr][c+2] = SCALE * bf2f((u16)(uv[1] & 0xffff));
    qs[rr][c+3] = SCALE * bf2f((u16)(uv[1] >> 16)); }
  for (int s = tid; s < 4*CAP; s += 256){
    int rr = s / CAP, ss = s - rr*CAP;
    idxl[rr][ss] = idxg[(long)(i0 + rr)*CAP + ss];
  }
  if (tid < 4) cntl[tid] = cntg[i0 + tid];
  if (DENSE){
    u32* dz = (u32*)&drow[0];
    #pragma unroll
    for (int t = tid; t < 2048; t += 256) dz[t] = 0;
  }
  __syncthreads();

  const int i = i0 + w;
  const int cnt = cntl[w];
  const int half = lane >> 5, lq = lane & 31;
  const int hh = lq >> 2;                 // head for this lane's 8-dim slice

  // ---- Phase A: scores; 4 K-rows per half in flight ----
  { const f32x4 q0 = *(const f32x4*)&qs[w][lq*8];
    const f32x4 q1 = *(const f32x4*)&qs[w][lq*8 + 4];
    int s = 0;
    for (; s + 8 <= cnt; s += 8){
      int j0 = idxl[w][s + half],     j1 = idxl[w][s + 2 + half];
      int j2 = idxl[w][s + 4 + half], j3 = idxl[w][s + 6 + half];
      bf16x8 k0 = ld_bf8(qkv + ((long)(b*Nn + j0))*768 + 256 + lq*8);
      bf16x8 k1 = ld_bf8(qkv + ((long)(b*Nn + j1))*768 + 256 + lq*8);
      bf16x8 k2 = ld_bf8(qkv + ((long)(b*Nn + j2))*768 + 256 + lq*8);
      bf16x8 k3 = ld_bf8(qkv + ((long)(b*Nn + j3))*768 + 256 + lq*8);
      float p0 = q0[0]*(float)k0[0] + q0[1]*(float)k0[1] + q0[2]*(float)k0[2] + q0[3]*(float)k0[3]
               + q1[0]*(float)k0[4] + q1[1]*(float)k0[5] + q1[2]*(float)k0[6] + q1[3]*(float)k0[7];
      float p1 = q0[0]*(float)k1[0] + q0[1]*(float)k1[1] + q0[2]*(float)k1[2] + q0[3]*(float)k1[3]
               + q1[0]*(float)k1[4] + q1[1]*(float)k1[5] + q1[2]*(float)k1[6] + q1[3]*(float)k1[7];
      float p2 = q0[0]*(float)k2[0] + q0[1]*(float)k2[1] + q0[2]*(float)k2[2] + q0[3]*(float)k2[3]
               + q1[0]*(float)k2[4] + q1[1]*(float)k2[5] + q1[2]*(float)k2[6] + q1[3]*(float)k2[7];
      float p3 = q0[0]*(float)k3[0] + q0[1]*(float)k3[1] + q0[2]*(float)k3[2] + q0[3]*(float)k3[3]
               + q1[0]*(float)k3[4] + q1[1]*(float)k3[5] + q1[2]*(float)k3[6] + q1[3]*(float)k3[7];
      p0 += __shfl_xor(p0, 1, 64); p0 += __shfl_xor(p0, 2, 64);
      p1 += __shfl_xor(p1, 1, 64); p1 += __shfl_xor(p1, 2, 64);
      p2 += __shfl_xor(p2, 1, 64); p2 += __shfl_xor(p2, 2, 64);
      p3 += __shfl_xor(p3, 1, 64); p3 += __shfl_xor(p3, 2, 64);
      if ((lq & 3) == 0){
        E[w][s + half][hh] = p0;     E[w][s + 2 + half][hh] = p1;
        E[w][s + 4 + half][hh] = p2; E[w][s + 6 + half][hh] = p3;
      }
    }
    for (; s + 2 <= cnt; s += 2){
      int j0 = idxl[w][s + half];
      bf16x8 k0 = ld_bf8(qkv + ((long)(b*Nn + j0))*768 + 256 + lq*8);
      float p0 = q0[0]*(float)k0[0] + q0[1]*(float)k0[1] + q0[2]*(float)k0[2] + q0[3]*(float)k0[3]
               + q1[0]*(float)k0[4] + q1[1]*(float)k0[5] + q1[2]*(float)k0[6] + q1[3]*(float)k0[7];
      p0 += __shfl_xor(p0, 1, 64); p0 += __shfl_xor(p0, 2, 64);
      if ((lq & 3) == 0) E[w][s + half][hh] = p0;
    }
    if (s < cnt){
      int j0 = idxl[w][s];
      bf16x8 k0 = ld_bf8(qkv + ((long)(b*Nn + j0))*768 + 256 + lq*8);
      float p0 = q0[0]*(float)k0[0] + q0[1]*(float)k0[1] + q0[2]*(float)k0[2] + q0[3]*(float)k0[3]
               + q1[0]*(float)k0[4] + q1[1]*(float)k0[5] + q1[2]*(float)k0[6] + q1[3]*(float)k0[7];
      p0 += __shfl_xor(p0, 1, 64); p0 += __shfl_xor(p0, 2, 64);
      if (half == 0 && (lq & 3) == 0) E[w][s][hh] = p0;
    }
  }
  __syncthreads();

  // ---- Phase B: per-head max/sum; lane = h*8+k owns slots s==k (mod 8) ----
  { const int h = lane >> 3, k = lane & 7;
    float m = -3.0e38f;
    for (int s = k; s < cnt; s += 8) m = fmaxf(m, E[w][s][h]);
    m = fmaxf(m, __shfl_xor(m, 1, 64));
    m = fmaxf(m, __shfl_xor(m, 2, 64));
    m = fmaxf(m, __shfl_xor(m, 4, 64));
    float l = 0.f;
    for (int s = k; s < cnt; s += 8){
      float e = __expf(E[w][s][h] - m);
      E[w][s][h] = e; l += e;
    }
    l += __shfl_xor(l, 1, 64);
    l += __shfl_xor(l, 2, 64);
    l += __shfl_xor(l, 4, 64);
    if (k == 0) invl[w][h] = 1.f / l;
  }
  __syncthreads();

  // ---- Phase C: a_mean; compact (amv) or LDS dense scatter (drow) ----
  { f32x4 i0v = *(f32x4*)&invl[w][0], i1v = *(f32x4*)&invl[w][4];
    for (int s = lane; s < cnt; s += 64){
      f32x4 e0 = *(f32x4*)&E[w][s][0], e1 = *(f32x4*)&E[w][s][4];
      float a = e0[0]*i0v[0] + e0[1]*i0v[1] + e0[2]*i0v[2] + e0[3]*i0v[3]
              + e1[0]*i1v[0] + e1[1]*i1v[1] + e1[2]*i1v[2] + e1[3]*i1v[3];
      a *= 0.125f;
      if (DENSE) drow[w*1024 + idxl[w][s]] = f2bf(a);
      else       amv[((long)(b*Nn + i))*CAP + s] = a;
    }
  }

  // ---- Phase D: PV; 4 V-rows per half in flight ----
  { f32x4 a0 = {0.f,0.f,0.f,0.f}, a1 = {0.f,0.f,0.f,0.f};
    int s = 0;
    for (; s + 8 <= cnt; s += 8){
      int j0 = idxl[w][s + half],     j1 = idxl[w][s + 2 + half];
      int j2 = idxl[w][s + 4 + half], j3 = idxl[w][s + 6 + half];
      bf16x8 v0 = ld_bf8(qkv + ((long)(b*Nn + j0))*768 + 512 + lq*8);
      bf16x8 v1 = ld_bf8(qkv + ((long)(b*Nn + j1))*768 + 512 + lq*8);
      bf16x8 v2 = ld_bf8(qkv + ((long)(b*Nn + j2))*768 + 512 + lq*8);
      bf16x8 v3 = ld_bf8(qkv + ((long)(b*Nn + j3))*768 + 512 + lq*8);
      float e0 = E[w][s + half][hh],     e1 = E[w][s + 2 + half][hh];
      float e2 = E[w][s + 4 + half][hh], e3 = E[w][s + 6 + half][hh];
      a0[0] += e0*(float)v0[0] + e1*(float)v1[0] + e2*(float)v2[0] + e3*(float)v3[0];
      a0[1] += e0*(float)v0[1] + e1*(float)v1[1] + e2*(float)v2[1] + e3*(float)v3[1];
      a0[2] += e0*(float)v0[2] + e1*(float)v1[2] + e2*(float)v2[2] + e3*(float)v3[2];
      a0[3] += e0*(float)v0[3] + e1*(float)v1[3] + e2*(float)v2[3] + e3*(float)v3[3];
      a1[0] += e0*(float)v0[4] + e1*(float)v1[4] + e2*(float)v2[4] + e3*(float)v3[4];
      a1[1] += e0*(float)v0[5] + e1*(float)v1[5] + e2*(float)v2[5] + e3*(float)v3[5];
      a1[2] += e0*(float)v0[6] + e1*(float)v1[6] + e2*(float)v2[6] + e3*(float)v3[6];
      a1[3] += e0*(float)v0[7] + e1*(float)v1[7] + e2*(float)v2[7] + e3*(float)v3[7];
    }
    for (; s + 2 <= cnt; s += 2){
      int j0 = idxl[w][s + half];
      bf16x8 v0 = ld_bf8(qkv + ((long)(b*Nn + j0))*768 + 512 + lq*8);
      float e0 = E[w][s + half][hh];
      a0[0] += e0*(float)v0[0]; a0[1] += e0*(float)v0[1];
      a0[2] += e0*(float)v0[2]; a0[3] += e0*(float)v0[3];
      a1[0] += e0*(float)v0[4]; a1[1] += e0*(float)v0[5];
      a1[2] += e0*(float)v0[6]; a1[3] += e0*(float)v0[7];
    }
    if (s < cnt && half == 0){
      int j0 = idxl[w][s];
      bf16x8 v0 = ld_bf8(qkv + ((long)(b*Nn + j0))*768 + 512 + lq*8);
      float e0 = E[w][s][hh];
      a0[0] += e0*(float)v0[0]; a0[1] += e0*(float)v0[1];
      a0[2] += e0*(float)v0[2]; a0[3] += e0*(float)v0[3];
      a1[0] += e0*(float)v0[4]; a1[1] += e0*(float)v0[5];
      a1[2] += e0*(float)v0[6]; a1[3] += e0*(float)v0[7];
    }
    #pragma unroll
    for (int p = 0; p < 4; ++p){
      a0[p] += __shfl_xor(a0[p], 32, 64);
      a1[p] += __shfl_xor(a1[p], 32, 64);
    }
    if (half == 0){
      float nl = invl[w][hh];
      u32x4 pb;
      pb[0] = (u32)f2bf(a0[0]*nl) | ((u32)f2bf(a0[1]*nl) << 16);
      pb[1] = (u32)f2bf(a0[2]*nl) | ((u32)f2bf(a0[3]*nl) << 16);
      pb[2] = (u32)f2bf(a1[0]*nl) | ((u32)f2bf(a1[1]*nl) << 16);
      pb[3] = (u32)f2bf(a1[2]*nl) | ((u32)f2bf(a1[3]*nl) << 16);
      *(u32x4*)(ob + ((long)(b*Nn + i)) * 256 + lq*8) = pb;
    }
  }

  // ---- dense row flush ----
  if (DENSE){
    __syncthreads();
    const u32x4* src = (const u32x4*)&drow[0];
    u32x4* dst = (u32x4*)(amd + ((long)(b*Nn + i0))*1024);
    #pragma unroll
    for (int t = tid; t < 512; t += 256) dst[t] = src[t];
  }
}

// ---------------- sparse chain: 4-way unrolled row gather ----------------
// grid (8192): b = bid&7 (XCD affinity), i = bid>>3
template<bool OUTF32>
__global__ __launch_bounds__(256) void sp_chain(
    const float* __restrict__ wts,        // [B*N][CAP] compact weights
    const u16* __restrict__ rows,         // [B*N][1024] dense bf16 rows
    const u16* __restrict__ idxg, const int* __restrict__ cntg,
    u16* __restrict__ dstb, float* __restrict__ dstf)
{
  __shared__ u16 idxl[CAP];
  __shared__ float wl[CAP];
  const int bid = blockIdx.x;
  const int b = bid & 7, i = bid >> 3;
  const int tid = threadIdx.x;
  const int cnt = cntg[i];
  if (tid < CAP){
    idxl[tid] = idxg[(long)i*CAP + tid];
    wl[tid]   = wts[((long)(b*Nn + i))*CAP + tid];
  }
  __syncthreads();
  f32x4 acc = {0.f, 0.f, 0.f, 0.f};
  const int c0 = tid * 4;
  int s = 0;
  for (; s + 4 <= cnt; s += 4){
    int j0 = idxl[s], j1 = idxl[s+1], j2 = idxl[s+2], j3 = idxl[s+3];
    float e0 = wl[s], e1 = wl[s+1], e2 = wl[s+2], e3 = wl[s+3];
    u32x2 r0 = *(const u32x2*)(rows + ((long)(b*Nn + j0))*1024 + c0);
    u32x2 r1 = *(const u32x2*)(rows + ((long)(b*Nn + j1))*1024 + c0);
    u32x2 r2 = *(const u32x2*)(rows + ((long)(b*Nn + j2))*1024 + c0);
    u32x2 r3 = *(const u32x2*)(rows + ((long)(b*Nn + j3))*1024 + c0);
    acc[0] += e0*bf2f((u16)(r0[0]&0xffff)) + e1*bf2f((u16)(r1[0]&0xffff))
            + e2*bf2f((u16)(r2[0]&0xffff)) + e3*bf2f((u16)(r3[0]&0xffff));
    acc[1] += e0*bf2f((u16)(r0[0]>>16)) + e1*bf2f((u16)(r1[0]>>16))
            + e2*bf2f((u16)(r2[0]>>16)) + e3*bf2f((u16)(r3[0]>>16));
    acc[2] += e0*bf2f((u16)(r0[1]&0xffff)) + e1*bf2f((u16)(r1[1]&0xffff))
            + e2*bf2f((u16)(r2[1]&0xffff)) + e3*bf2f((u16)(r3[1]&0xffff));
    acc[3] += e0*bf2f((u16)(r0[1]>>16)) + e1*bf2f((u16)(r1[1]>>16))
            + e2*bf2f((u16)(r2[1]>>16)) + e3*bf2f((u16)(r3[1]>>16));
  }
  for (; s < cnt; ++s){
    int j0 = idxl[s];
    float e0 = wl[s];
    u32x2 r0 = *(const u32x2*)(rows + ((long)(b*Nn + j0))*1024 + c0);
    acc[0] += e0*bf2f((u16)(r0[0]&0xffff));
    acc[1] += e0*bf2f((u16)(r0[0]>>16));
    acc[2] += e0*bf2f((u16)(r0[1]&0xffff));
    acc[3] += e0*bf2f((u16)(r0[1]>>16));
  }
  if (OUTF32){
    *(f32x4*)(dstf + ((long)(b*Nn + i))*1024 + c0) = acc;
  } else {
    u32x2 pb;
    pb[0] = (u32)f2bf(acc[0]) | ((u32)f2bf(acc[1]) << 16);
    pb[1] = (u32)f2bf(acc[2]) | ((u32)f2bf(acc[3]) << 16);
    *(u32x2*)(dstb + ((long)(b*Nn + i))*1024 + c0) = pb;
  }
}

// ---------------- residual + layernorm ----------------
__global__ __launch_bounds__(256) void ln_kernel(
    const float* __restrict__ hin, const float* __restrict__ y,
    float* __restrict__ hout, u16* __restrict__ hb, float* __restrict__ outf,
    const float* __restrict__ g, const float* __restrict__ be)
{
  int row  = blockIdx.x * 4 + (threadIdx.x >> 6);
  int lane = threadIdx.x & 63;
  f32x4 v = *(const f32x4*)(hin + (long)row*Dd + lane*4)
          + *(const f32x4*)(y   + (long)row*Dd + lane*4);
  float s = v[0] + v[1] + v[2] + v[3];
  #pragma unroll
  for (int off = 32; off; off >>= 1) s += __shfl_xor(s, off, 64);
  float mu = s * (1.f/256.f);
  f32x4 d = v - mu;
  float q2 = d[0]*d[0] + d[1]*d[1] + d[2]*d[2] + d[3]*d[3];
  #pragma unroll
  for (int off = 32; off; off >>= 1) q2 += __shfl_xor(q2, off, 64);
  float rs = rsqrtf(q2 * (1.f/256.f) + 1e-5f);
  f32x4 ov;
  #pragma unroll
  for (int p = 0; p < 4; ++p)
    ov[p] = d[p] * rs * g[lane*4 + p] + be[lane*4 + p];
  *(f32x4*)(hout + (long)row*Dd + lane*4) = ov;
  if (hb){
    u32x2 pb;
    pb[0] = (u32)f2bf(ov[0]) | ((u32)f2bf(ov[1]) << 16);
    pb[1] = (u32)f2bf(ov[2]) | ((u32)f2bf(ov[3]) << 16);
    *(u32x2*)(hb + (long)row*Dd + lane*4) = pb;
  }
  if (outf)
    *(f32x4*)(outf + (long)row*Dd + lane*4) = ov;
}

extern "C" void kernel_launch(void* const* d_in, const int* in_sizes, int n_in,
                              void* d_out, int out_size, void* d_ws, size_t ws_size,
                              hipStream_t stream)
{
  (void)in_sizes; (void)n_in; (void)out_size; (void)ws_size;
  const float* x   = (const float*)d_in[0];
  const float* adj = (const float*)d_in[1];
  const float* W0  = (const float*)d_in[2];
  const float* Wq  = (const float*)d_in[3];
  const float* bq  = (const float*)d_in[4];
  const float* Wk  = (const float*)d_in[5];
  const float* bk  = (const float*)d_in[6];
  const float* Wv  = (const float*)d_in[7];
  const float* bv  = (const float*)d_in[8];
  const float* Wo  = (const float*)d_in[9];
  const float* bo  = (const float*)d_in[10];
  const float* gm  = (const float*)d_in[11];
  const float* bt  = (const float*)d_in[12];
  float* outf  = (float*)d_out;                 // f32 h region [8,1024,256]
  float* outat = outf + (long)Bb * Nn * Dd;     // f32 atten region [8,1024,1024]

  // ---- workspace (~83MB < proven 92MB) ----
  char* w = (char*)d_ws;
  u16* W0b  = (u16*)w; w += 131072;             // W0|Wq|Wk|Wv|Wo contiguous (conv_w5)
  u16* Wqb  = (u16*)w; w += 4*393216;
  float* bqkv = (float*)w; w += 9216;           // [3][768]
  u32* bitsg = (u32*)w; w += 131072;
  u16* idxg  = (u16*)w; w += 1024*CAP*2;        // 192KB
  int* cntg  = (int*)w; w += 4096;
  u16* xb  = (u16*)w; w += 4194304;
  u16* hb  = (u16*)w; w += 4194304;
  u16* qkv = (u16*)w; w += (long)Bb*Nn*768*2;   // 12MB
  u16* ob  = (u16*)w; w += 4194304;
  float* hbuf = (float*)w; w += 8388608;
  float* ybuf = (float*)w; w += 8388608;
  float* amv1 = (float*)w; w += (long)Bb*Nn*CAP*4;  // 3MB
  float* amv2 = (float*)w; w += (long)Bb*Nn*CAP*4;  // 3MB
  u16* P1   = (u16*)w; w += 16777216;           // [8][1024][1024] bf16
  u16* am0d = (u16*)w; w += 16777216;           // dense am0 [8][1024][1024] bf16

  dim3 blk(256);
  f32_to_bf16<<<2048, blk, 0, stream>>>(x, xb, 2097152);
  conv_w5<<<833, blk, 0, stream>>>(W0, Wq, Wk, Wv, Wo, W0b, bq, bk, bv, bqkv);
  adj_to_bits<<<128, blk, 0, stream>>>(adj, bitsg);
  nbr_build<<<4, blk, 0, stream>>>(bitsg, idxg, cntg);

  // input projection: h = x @ W0^T  (f32 + bf16)
  gemm_bt<false,false,true,true><<<dim3(2,64,1), blk, 0, stream>>>(
      xb, 256, 0, W0b, 256, 0, hbuf, hb, 256, 0, 256, nullptr, 0, nullptr);

  for (int l = 0; l < 3; ++l){
    // fused q|k|v projection
    gemm_bt<true,false,false,true><<<dim3(2,64,3), blk, 0, stream>>>(
        hb, 256, 0, Wqb + (long)l*65536, 256, 196608,
        nullptr, qkv, 768, 256, 256, bqkv + l*768, 256, nullptr);
    // sparse attention (XCD affinity): l0 dense am0d, l1/l2 compact
    if (l == 0)
      attn_sparse<1><<<dim3(2048), blk, 0, stream>>>(
          qkv, ob, idxg, cntg, nullptr, am0d);
    else
      attn_sparse<0><<<dim3(2048), blk, 0, stream>>>(
          qkv, ob, idxg, cntg, (l == 1 ? amv1 : amv2), nullptr);
    // y = o @ Wo^T + bo (f32)
    gemm_bt<true,false,true,false><<<dim3(2,64,1), blk, 0, stream>>>(
        ob, 256, 0, Wqb + (long)(3*3+l)*65536, 256, 0, ybuf, nullptr, 256, 0, 256,
        bo + l*256, 0, nullptr);
    // h = LN(h + y)
    ln_kernel<<<dim3(2048), blk, 0, stream>>>(
        hbuf, ybuf, hbuf, (l < 2 ? hb : nullptr), (l < 2 ? nullptr : outf),
        gm + l*256, bt + l*256);
    // chain: P1 = am1 @ am0d (bf16); final = am2 @ P1 (f32 -> d_out)
    if (l == 1)
      sp_chain<false><<<dim3(8192), blk, 0, stream>>>(
          amv1, am0d, idxg, cntg, P1, nullptr);
    if (l == 2)
      sp_chain<true><<<dim3(8192), blk, 0, stream>>>(
          amv2, P1, idxg, cntg, nullptr, outat);
  }
}